// Round 7
// baseline (798.028 us; speedup 1.0000x reference)
//
#include <hip/hip_runtime.h>
#include <cstddef>
#include <cstdint>

// Problem constants
#define B_  4096
#define I_  512
#define L_  128
#define D_  512
#define E_  8
#define H_  512
#define HR_ 256
#define A_  32

typedef __attribute__((ext_vector_type(8))) __bf16 bf16x8;
typedef __attribute__((ext_vector_type(4))) __bf16 bf16x4;
typedef __attribute__((ext_vector_type(4))) float floatx4;

__device__ __forceinline__ float sigmoidf_(float x) { return 1.0f / (1.0f + __expf(-x)); }

__device__ __forceinline__ void load_lds16(const void* g, void* l) {
    __builtin_amdgcn_global_load_lds((__attribute__((address_space(1))) void*)g,
                                     (__attribute__((address_space(3))) void*)l, 16, 0, 0);
}

struct HiLo { __bf16 h, l; };
__device__ __forceinline__ HiLo hi_lo(float v) {
    HiLo r;
    r.h = (__bf16)v;
    r.l = (__bf16)(v - (float)r.h);
    return r;
}
__device__ __forceinline__ void split4(float4 v, bf16x4& hi, bf16x4& lo) {
    HiLo a = hi_lo(v.x), b = hi_lo(v.y), c = hi_lo(v.z), d = hi_lo(v.w);
    hi = (bf16x4){a.h, b.h, c.h, d.h};
    lo = (bf16x4){a.l, b.l, c.l, d.l};
}

// ---------------- conversion kernels ----------------
__global__ __launch_bounds__(256) void f2b_k(const float* __restrict__ src,
                                             __bf16* __restrict__ dst, int n4) {
    int i = blockIdx.x * 256 + threadIdx.x;
    if (i < n4) {
        float4 v = ((const float4*)src)[i];
        bf16x4 o = { (__bf16)v.x, (__bf16)v.y, (__bf16)v.z, (__bf16)v.w };
        *(bf16x4*)(dst + (size_t)i * 4) = o;
    }
}

// W (N,K) fp32 -> out (N,2K) bf16 = [W_hi | W_lo] per row
__global__ __launch_bounds__(256) void wcat2_k(const float* __restrict__ W,
                                               __bf16* __restrict__ out,
                                               int K4, int n4tot) {
    int i4 = blockIdx.x * 256 + threadIdx.x;
    if (i4 >= n4tot) return;
    int row = i4 / K4;
    int c4  = i4 - row * K4;
    const int K = K4 * 4;
    float4 v = ((const float4*)W)[i4];
    bf16x4 hi, lo;
    split4(v, hi, lo);
    __bf16* dst = out + (size_t)row * 2 * K + c4 * 4;
    *(bf16x4*)(dst)     = hi;
    *(bf16x4*)(dst + K) = lo;
}

// [x (B,512) | lang (B,128)] -> xcat (B,1920) = [hi | hi | lo]
__global__ __launch_bounds__(256) void concat_cat_k(const float* __restrict__ x,
                                                    const float* __restrict__ lang,
                                                    __bf16* __restrict__ out) {
    int idx = blockIdx.x * 256 + threadIdx.x;   // over B_*160 float4 groups
    int b = idx / 160;
    int c = idx - b * 160;
    float4 v;
    if (c < 128) v = ((const float4*)x)[(size_t)b * 128 + c];
    else         v = ((const float4*)lang)[(size_t)b * 32 + (c - 128)];
    bf16x4 hi, lo;
    split4(v, hi, lo);
    __bf16* dst = out + (size_t)b * 1920 + c * 4;
    *(bf16x4*)(dst)        = hi;
    *(bf16x4*)(dst + 640)  = hi;
    *(bf16x4*)(dst + 1280) = lo;
}

// xp fp32 (B,512) -> xp_cat (B,1536) = [hi | hi | lo]
__global__ __launch_bounds__(256) void split2cat_k(const float* __restrict__ src,
                                                   __bf16* __restrict__ out) {
    int i4 = blockIdx.x * 256 + threadIdx.x;    // over B_*128
    int b = i4 >> 7;
    int c4 = i4 & 127;
    float4 v = ((const float4*)src)[i4];
    bf16x4 hi, lo;
    split4(v, hi, lo);
    __bf16* dst = out + (size_t)b * 1536 + c4 * 4;
    *(bf16x4*)(dst)         = hi;
    *(bf16x4*)(dst + 512)   = hi;
    *(bf16x4*)(dst + 1024)  = lo;
}

// h_e chunk convert: (E, B, H) fp32 rows [r0, r0+2048) -> (E, 2048, H) bf16
__global__ __launch_bounds__(256) void f2bhe_k(const float* __restrict__ he,
                                               __bf16* __restrict__ dst, int r0) {
    int i4 = blockIdx.x * 256 + threadIdx.x;    // over 8*2048*128
    int e   = i4 >> 18;
    int rem = i4 & 262143;
    int row = rem >> 7;
    int c4  = rem & 127;
    float4 v = ((const float4*)he)[(size_t)e * (B_ * 128) + (size_t)(r0 + row) * 128 + c4];
    bf16x4 o = { (__bf16)v.x, (__bf16)v.y, (__bf16)v.z, (__bf16)v.w };
    *(bf16x4*)(dst + (size_t)i4 * 4) = o;
}

// =====================================================================
// LDS subtile layout (all MFMA kernels below): each global_load_lds writes
// one 1024-B subtile = 16 rows x 32 k of bf16, stored [kseg(4)][row(16)][8elem]
// via PRE-SWIZZLED GLOBAL SOURCE: staging lane L fetches row (L&15),
// kseg (L>>4) -> LDS dest base+L*16 (linear, as gload_lds requires).
// Fragment read for mfma_16x16x32: lane L needs [row L&15][k (L>>4)*8..+8]
// = subtile_base + L*16 -> CONTIGUOUS 1024-B wave read, zero bank conflicts
// (old [row][32k] layout was ~8-way aliased: 10.5M conflict-cycles/dispatch).
// =====================================================================

// ---------------- MFMA GEMM (2-phase double-buffered, swizzled subtiles) ----
template<int MODE, bool XORD>
__global__ __launch_bounds__(256) void mgemm(
    const __bf16* __restrict__ A, long long aBatch,
    const __bf16* __restrict__ Bw, long long bBatch, int bRS, int kWrap,
    const float* __restrict__ bias, long long biasBatch,
    float* __restrict__ Cv, long long cBatch,
    int N, int K,
    const float* __restrict__ scale, int sstride, int szBatch)
{
    constexpr int ASZ = 128 * 32;
    __shared__ __align__(16) __bf16 As[2 * ASZ];
    __shared__ __align__(16) __bf16 Bs[2 * ASZ];

    const int tid  = threadIdx.x;
    const int w    = tid >> 6;
    const int lane = tid & 63;
    const int m0 = (XORD ? blockIdx.z : blockIdx.x) * 128;
    const int n0 = blockIdx.y * 128;
    const int z  = XORD ? blockIdx.x : blockIdx.z;

    // staging source: row (lane&15), kseg (lane>>4) -- see layout note above
    const int lrow = lane & 15;
    const int lk   = lane >> 4;
    const __bf16* Ag0 = A + (size_t)z * aBatch + (size_t)(m0 + w * 32 + lrow) * K + lk * 8;
    const __bf16* Ag1 = Ag0 + (size_t)16 * K;
    const __bf16* Bg0 = Bw + (size_t)z * bBatch + (size_t)(n0 + w * 32 + lrow) * bRS + lk * 8;
    const __bf16* Bg1 = Bg0 + (size_t)16 * bRS;

    const int wm = w & 1, wn = w >> 1;
    const int lr16 = lane & 15;
    const int lq   = lane >> 4;

    floatx4 acc[4][4];
#pragma unroll
    for (int i = 0; i < 4; ++i)
#pragma unroll
        for (int j = 0; j < 4; ++j) acc[i][j] = (floatx4){0.f, 0.f, 0.f, 0.f};

    const int NSTEP = K >> 5;

    auto STAGE = [&](int s, int buf) {
        const int k0 = s << 5;
        const int kb = (k0 < kWrap) ? k0 : (k0 - kWrap);
        __bf16* al = As + buf * ASZ + (w * 32) * 32;
        __bf16* bl = Bs + buf * ASZ + (w * 32) * 32;
        load_lds16(Ag0 + k0, al);
        load_lds16(Ag1 + k0, al + 16 * 32);
        load_lds16(Bg0 + kb, bl);
        load_lds16(Bg1 + kb, bl + 16 * 32);
    };

    int cur = 0;
    STAGE(0, 0);
    __syncthreads();
    for (int s = 0; s < NSTEP; ++s) {
        if (s + 1 < NSTEP) STAGE(s + 1, cur ^ 1);

        // subtile stride = 512 elems; lane offset = lane*8 elems (linear read)
        const __bf16* Af = As + cur * ASZ + wm * 2048 + lane * 8;
        const __bf16* Bf = Bs + cur * ASZ + wn * 2048 + lane * 8;
        bf16x8 af[4], bfr[4];
#pragma unroll
        for (int t = 0; t < 4; ++t) {
            af[t]  = *(const bf16x8*)(Af + t * 512);
            bfr[t] = *(const bf16x8*)(Bf + t * 512);
        }
#pragma unroll
        for (int tm = 0; tm < 4; ++tm)
#pragma unroll
            for (int tn = 0; tn < 4; ++tn)
                acc[tm][tn] = __builtin_amdgcn_mfma_f32_16x16x32_bf16(af[tm], bfr[tn], acc[tm][tn], 0, 0, 0);

        __syncthreads();
        cur ^= 1;
    }

    const float* biasz = bias + (size_t)z * biasBatch;
    const int sz = z * szBatch;
#pragma unroll
    for (int tm = 0; tm < 4; ++tm) {
        const int mbase = m0 + wm * 64 + tm * 16 + lq * 4;
#pragma unroll
        for (int r = 0; r < 4; ++r) {
            const int m = mbase + r;
            float wsc = 0.f;
            if (MODE == 2) wsc = scale[(size_t)m * sstride + sz];
#pragma unroll
            for (int tn = 0; tn < 4; ++tn) {
                const int n = n0 + wn * 64 + tn * 16 + lr16;
                float v = acc[tm][tn][r] + biasz[n];
                const size_t ci = (size_t)z * cBatch + (size_t)m * N + n;
                if (MODE == 0) Cv[ci] = v;
                else           Cv[ci] = wsc * v;
            }
        }
    }
}

// ---------------- router fused gh-GEMM + GRU (swizzled subtiles) ----------------
template<int HD, bool WRITE_HNEW, bool XORD>
__global__ __launch_bounds__(256) void fgru(
    const __bf16* __restrict__ Ab, long long aBatch,     // (z, Mtot, HD) bf16
    const __bf16* __restrict__ Whh, long long wBatch,    // (z, 3HD, HD) bf16
    const float* __restrict__ bhh, long long bhhBatch,   // (z, 3HD)
    const float* __restrict__ gx, long long gxBatch,     // (z, Mtot, 3HD) fp32
    const float* __restrict__ hprev, long long hBatch,   // (z, ..., HD) fp32
    float* __restrict__ hout, long long hoBatch,         // fp32
    __bf16* __restrict__ hnew, long long hnBatch)        // bf16
{
    __shared__ __align__(16) __bf16 As[128 * 32];
    __shared__ __align__(16) __bf16 Bs[192 * 32];

    const int tid  = threadIdx.x;
    const int w    = tid >> 6;
    const int lane = tid & 63;
    const int m0 = (XORD ? blockIdx.z : blockIdx.x) * 128;
    const int j0 = blockIdx.y * 64;
    const int z  = XORD ? blockIdx.x : blockIdx.z;

    const int lrow = lane & 15;
    const int lk   = lane >> 4;
    const __bf16* Ag0 = Ab + (size_t)z * aBatch + (size_t)(m0 + w * 32 + lrow) * HD + lk * 8;
    const __bf16* Ag1 = Ag0 + (size_t)16 * HD;
    __bf16* Al0 = As + (w * 32) * 32;
    __bf16* Al1 = Al0 + 16 * 32;

    const __bf16* Wz = Whh + (size_t)z * wBatch;
    const __bf16* Bg[3];
    __bf16* Bl[3];
#pragma unroll
    for (int i = 0; i < 3; ++i) {
        const int r = (w * 3 + i) * 16 + lrow;          // 0..191
        const int gate = r >> 6;
        const int grow = gate * HD + j0 + (r & 63);
        Bg[i] = Wz + (size_t)grow * HD + lk * 8;
        Bl[i] = Bs + ((w * 3 + i) * 16) * 32;
    }

    const int mh = w & 1, nh = w >> 1;
    const int lr16 = lane & 15;
    const int lq   = lane >> 4;
    const __bf16* Af = As + mh * 2048 + lane * 8;
    const __bf16* Bf = Bs + nh * 1024 + lane * 8;

    floatx4 acc[3][4][2];
#pragma unroll
    for (int g = 0; g < 3; ++g)
#pragma unroll
        for (int i = 0; i < 4; ++i)
#pragma unroll
            for (int j = 0; j < 2; ++j) acc[g][i][j] = (floatx4){0.f, 0.f, 0.f, 0.f};

    for (int k0 = 0; k0 < HD; k0 += 32) {
        __syncthreads();
        load_lds16(Ag0 + k0, Al0);
        load_lds16(Ag1 + k0, Al1);
#pragma unroll
        for (int i = 0; i < 3; ++i) load_lds16(Bg[i] + k0, Bl[i]);
        __syncthreads();

        bf16x8 af[4], bf[3][2];
#pragma unroll
        for (int t = 0; t < 4; ++t) af[t] = *(const bf16x8*)(Af + t * 512);
#pragma unroll
        for (int g = 0; g < 3; ++g)
#pragma unroll
            for (int tn = 0; tn < 2; ++tn)
                bf[g][tn] = *(const bf16x8*)(Bf + (g * 4 + tn) * 512);
#pragma unroll
        for (int g = 0; g < 3; ++g)
#pragma unroll
            for (int tm = 0; tm < 4; ++tm)
#pragma unroll
                for (int tn = 0; tn < 2; ++tn)
                    acc[g][tm][tn] = __builtin_amdgcn_mfma_f32_16x16x32_bf16(af[tm], bf[g][tn], acc[g][tm][tn], 0, 0, 0);
    }

    const float* bhhz = bhh + (size_t)z * bhhBatch;
#pragma unroll
    for (int tm = 0; tm < 4; ++tm) {
#pragma unroll
        for (int rr = 0; rr < 4; ++rr) {
            const int row = m0 + mh * 64 + tm * 16 + lq * 4 + rr;
            const float* gxrow = gx + (size_t)z * gxBatch + (size_t)row * (3 * HD);
            const float* hrow  = hprev + (size_t)z * hBatch + (size_t)row * HD;
#pragma unroll
            for (int tn = 0; tn < 2; ++tn) {
                const int j = j0 + nh * 32 + tn * 16 + lr16;
                float ghr = acc[0][tm][tn][rr] + bhhz[j];
                float ghz = acc[1][tm][tn][rr] + bhhz[HD + j];
                float ghn = acc[2][tm][tn][rr] + bhhz[2 * HD + j];
                float r  = sigmoidf_(gxrow[j] + ghr);
                float zz = sigmoidf_(gxrow[HD + j] + ghz);
                float n  = tanhf(gxrow[2 * HD + j] + r * ghn);
                float hv = hrow[j];
                float o  = (1.f - zz) * n + zz * hv;
                hout[(size_t)z * hoBatch + (size_t)row * HD + j] = o;
                if (WRITE_HNEW)
                    hnew[(size_t)z * hnBatch + (size_t)row * HD + j] = (__bf16)o;
            }
        }
    }
}

// ---------------- fused expert gx+gh GEMM + GRU (depth-3 + swizzle + setprio) ----
template<int MROWS>
__global__ __launch_bounds__(256, 2) void fxgru_k(
    const __bf16* __restrict__ xpc,     // (MROWS, 1536) chunk [hi|hi|lo]
    const __bf16* __restrict__ Wih,     // (E, 1536, 1024) rows [hi|lo]
    const float* __restrict__ bih,      // (E, 1536)
    const __bf16* __restrict__ heb,     // (E, MROWS, 512) bf16 h_prev chunk
    const __bf16* __restrict__ Whh,     // (E, 1536, 512) bf16
    const float* __restrict__ bhh,      // (E, 1536)
    const float* __restrict__ hprev,    // (E, B, 512) fp32, chunk base
    long long hBatch,
    float* __restrict__ hout,           // (E, B, 512) fp32, chunk base
    long long hoBatch,
    __bf16* __restrict__ hnew)          // (E, MROWS, 512) bf16
{
    constexpr int ASZ = 128 * 32;
    constexpr int BSZ = 192 * 32;
    __shared__ __align__(16) __bf16 As[3 * ASZ];   // 24 KB
    __shared__ __align__(16) __bf16 Bs[3 * BSZ];   // 36 KB  (total 60 KB, 2 blk/CU)

    const int tid  = threadIdx.x;
    const int w    = tid >> 6;
    const int lane = tid & 63;
    const int z  = blockIdx.x;          // expert -> XCD
    const int j0 = blockIdx.y * 64;
    const int m0 = blockIdx.z * 128;

    const int lrow = lane & 15;         // staging: row within subtile
    const int lk   = lane >> 4;         // staging: k-seg
    const int aoff = (w * 32) * 32;
    int BlOff[3];
#pragma unroll
    for (int i = 0; i < 3; ++i) BlOff[i] = ((w * 3 + i) * 16) * 32;

    const int mh = w & 1, nh = w >> 1;
    const int lr16 = lane & 15;
    const int lq   = lane >> 4;

    floatx4 acc[3][4][2];   // gate r/z: gx+gh summed in place; gate n: gx only
    floatx4 accn[4][2];     // gh n-gate (kept separate for r*gh_n)
#pragma unroll
    for (int g = 0; g < 3; ++g)
#pragma unroll
        for (int i = 0; i < 4; ++i)
#pragma unroll
            for (int j = 0; j < 2; ++j) acc[g][i][j] = (floatx4){0.f, 0.f, 0.f, 0.f};
#pragma unroll
    for (int i = 0; i < 4; ++i)
#pragma unroll
        for (int j = 0; j < 2; ++j) accn[i][j] = (floatx4){0.f, 0.f, 0.f, 0.f};

    auto COMPA = [&](int buf) {
        const __bf16* Af = As + buf * ASZ + mh * 2048 + lane * 8;
        const __bf16* Bf = Bs + buf * BSZ + nh * 1024 + lane * 8;
        bf16x8 af[4], bf[3][2];
#pragma unroll
        for (int t = 0; t < 4; ++t) af[t] = *(const bf16x8*)(Af + t * 512);
#pragma unroll
        for (int g = 0; g < 3; ++g)
#pragma unroll
            for (int tn = 0; tn < 2; ++tn)
                bf[g][tn] = *(const bf16x8*)(Bf + (g * 4 + tn) * 512);
        __builtin_amdgcn_s_setprio(1);
#pragma unroll
        for (int g = 0; g < 3; ++g)
#pragma unroll
            for (int tm = 0; tm < 4; ++tm)
#pragma unroll
                for (int tn = 0; tn < 2; ++tn)
                    acc[g][tm][tn] = __builtin_amdgcn_mfma_f32_16x16x32_bf16(af[tm], bf[g][tn], acc[g][tm][tn], 0, 0, 0);
        __builtin_amdgcn_s_setprio(0);
    };
    auto COMPB = [&](int buf) {
        const __bf16* Af = As + buf * ASZ + mh * 2048 + lane * 8;
        const __bf16* Bf = Bs + buf * BSZ + nh * 1024 + lane * 8;
        bf16x8 af[4], bf[3][2];
#pragma unroll
        for (int t = 0; t < 4; ++t) af[t] = *(const bf16x8*)(Af + t * 512);
#pragma unroll
        for (int g = 0; g < 3; ++g)
#pragma unroll
            for (int tn = 0; tn < 2; ++tn)
                bf[g][tn] = *(const bf16x8*)(Bf + (g * 4 + tn) * 512);
        __builtin_amdgcn_s_setprio(1);
#pragma unroll
        for (int tm = 0; tm < 4; ++tm)
#pragma unroll
            for (int tn = 0; tn < 2; ++tn) {
                acc[0][tm][tn] = __builtin_amdgcn_mfma_f32_16x16x32_bf16(af[tm], bf[0][tn], acc[0][tm][tn], 0, 0, 0);
                acc[1][tm][tn] = __builtin_amdgcn_mfma_f32_16x16x32_bf16(af[tm], bf[1][tn], acc[1][tm][tn], 0, 0, 0);
                accn[tm][tn]   = __builtin_amdgcn_mfma_f32_16x16x32_bf16(af[tm], bf[2][tn], accn[tm][tn], 0, 0, 0);
            }
        __builtin_amdgcn_s_setprio(0);
    };

    // wait for own tile-loads (leave N in flight) then workgroup barrier
#define TILE_WAIT(N) do { \
        asm volatile("s_waitcnt vmcnt(" #N ")" ::: "memory"); \
        __builtin_amdgcn_s_barrier(); \
        __builtin_amdgcn_sched_barrier(0); \
    } while (0)
#define READ_DONE() do { \
        __builtin_amdgcn_sched_barrier(0); \
        __builtin_amdgcn_s_barrier(); \
    } while (0)

    int cur = 0;
    // ================= phase A: gx, tiles 0..47 =================
    {
        const __bf16* AgA0 = xpc + (size_t)(m0 + w * 32 + lrow) * 1536 + lk * 8;
        const __bf16* AgA1 = AgA0 + (size_t)16 * 1536;
        const __bf16* WihZ = Wih + (size_t)z * (1536 * 1024);
        const __bf16* BgA[3];
#pragma unroll
        for (int i = 0; i < 3; ++i) {
            const int r = (w * 3 + i) * 16 + lrow;          // 0..191
            const int grow = (r >> 6) * 512 + j0 + (r & 63);
            BgA[i] = WihZ + (size_t)grow * 1024 + lk * 8;
        }
        auto STAGE_A = [&](int s, int buf) {
            const int k0 = s << 5;
            const int kb = (k0 < 1024) ? k0 : (k0 - 1024);
            __bf16* al = As + buf * ASZ + aoff;
            __bf16* bl = Bs + buf * BSZ;
            load_lds16(AgA0 + k0, al);
            load_lds16(AgA1 + k0, al + 16 * 32);
#pragma unroll
            for (int i = 0; i < 3; ++i) load_lds16(BgA[i] + kb, bl + BlOff[i]);
        };

        STAGE_A(0, 0);
        STAGE_A(1, 1);
        STAGE_A(2, 2);                    // 15 loads in flight
        for (int s = 0; s < 45; ++s) {    // tiles 0..44; stage tiles 3..47
            TILE_WAIT(10);
            COMPA(cur);
            READ_DONE();
            STAGE_A(s + 3, cur);
            cur = (cur == 2) ? 0 : cur + 1;
        }
    }
    // ================= boundary: finish A tiles 45..47, stage B 0..2 =========
    {
        const __bf16* AgB0 = heb + (size_t)z * (MROWS * 512)
                                 + (size_t)(m0 + w * 32 + lrow) * 512 + lk * 8;
        const __bf16* AgB1 = AgB0 + (size_t)16 * 512;
        const __bf16* WhhZ = Whh + (size_t)z * (1536 * 512);
        const __bf16* BgB[3];
#pragma unroll
        for (int i = 0; i < 3; ++i) {
            const int r = (w * 3 + i) * 16 + lrow;
            const int grow = (r >> 6) * 512 + j0 + (r & 63);
            BgB[i] = WhhZ + (size_t)grow * 512 + lk * 8;
        }
        auto STAGE_B = [&](int t, int buf) {
            const int k0 = t << 5;
            __bf16* al = As + buf * ASZ + aoff;
            __bf16* bl = Bs + buf * BSZ;
            load_lds16(AgB0 + k0, al);
            load_lds16(AgB1 + k0, al + 16 * 32);
#pragma unroll
            for (int i = 0; i < 3; ++i) load_lds16(BgB[i] + k0, bl + BlOff[i]);
        };

#pragma unroll
        for (int q = 0; q < 3; ++q) {     // A tiles 45,46,47; stage B 0,1,2
            TILE_WAIT(10);
            COMPA(cur);
            READ_DONE();
            STAGE_B(q, cur);
            cur = (cur == 2) ? 0 : cur + 1;
        }
        // ================= phase B: gh, tiles 0..15 =================
        for (int t = 0; t < 13; ++t) {    // stage tiles 3..15
            TILE_WAIT(10);
            COMPB(cur);
            READ_DONE();
            STAGE_B(t + 3, cur);
            cur = (cur == 2) ? 0 : cur + 1;
        }
        TILE_WAIT(10);                    // tile 13 (14,15 in flight)
        COMPB(cur);
        cur = (cur == 2) ? 0 : cur + 1;
        TILE_WAIT(5);                     // tile 14
        COMPB(cur);
        cur = (cur == 2) ? 0 : cur + 1;
        TILE_WAIT(0);                     // tile 15
        COMPB(cur);
    }
#undef TILE_WAIT
#undef READ_DONE

    // ---- GRU epilogue ----
    const float* bihz = bih + (size_t)z * 1536;
    const float* bhhz = bhh + (size_t)z * 1536;
#pragma unroll
    for (int tm = 0; tm < 4; ++tm) {
#pragma unroll
        for (int rr = 0; rr < 4; ++rr) {
            const int row = m0 + mh * 64 + tm * 16 + lq * 4 + rr;
            const float* hrow = hprev + (size_t)z * hBatch + (size_t)row * 512;
#pragma unroll
            for (int tn = 0; tn < 2; ++tn) {
                const int j = j0 + nh * 32 + tn * 16 + lr16;
                float gr  = acc[0][tm][tn][rr] + bihz[j] + bhhz[j];
                float gz  = acc[1][tm][tn][rr] + bihz[512 + j] + bhhz[512 + j];
                float gxn = acc[2][tm][tn][rr] + bihz[1024 + j];
                float ghn = accn[tm][tn][rr] + bhhz[1024 + j];
                float r  = sigmoidf_(gr);
                float zz = sigmoidf_(gz);
                float n  = tanhf(gxn + r * ghn);
                float hv = hrow[j];
                float o  = (1.f - zz) * n + zz * hv;
                hout[(size_t)z * hoBatch + (size_t)row * 512 + j] = o;
                hnew[(size_t)z * (MROWS * 512) + (size_t)row * 512 + j] = (__bf16)o;
            }
        }
    }
}

// ---------------- router fc + softmax ----------------
__global__ __launch_bounds__(256) void fc_softmax_k(const float* __restrict__ hr,
                                                    const float* __restrict__ Wfc,
                                                    const float* __restrict__ bfc,
                                                    float* __restrict__ wts) {
    int lane = threadIdx.x & 63;
    int wave = threadIdx.x >> 6;
    int rg = lane >> 3;
    int e  = lane & 7;
    int b  = blockIdx.x * 32 + wave * 8 + rg;
    const float* h = hr + (size_t)b * HR_;
    const float* w = Wfc + (size_t)e * HR_;
    float acc = 0.0f;
#pragma unroll 4
    for (int k = 0; k < HR_; k += 4) {
        float4 hv = *(const float4*)(h + k);
        float4 wv = *(const float4*)(w + k);
        acc += hv.x * wv.x + hv.y * wv.y + hv.z * wv.z + hv.w * wv.w;
    }
    acc += bfc[e];
    float m = acc;
    for (int off = 4; off; off >>= 1) m = fmaxf(m, __shfl_xor(m, off, 8));
    float ex = __expf(acc - m);
    float s = ex;
    for (int off = 4; off; off >>= 1) s += __shfl_xor(s, off, 8);
    wts[(size_t)b * E_ + e] = ex / s;
}

// ---------------- reduce 8 expert P planes (chunk) -> comb ----------------
__global__ __launch_bounds__(256) void reduce8_k(const float* __restrict__ P,
                                                 float* __restrict__ comb,
                                                 int n4, int ps4) {
    int i = blockIdx.x * 256 + threadIdx.x;
    if (i >= n4) return;
    float4 s = ((const float4*)P)[i];
#pragma unroll
    for (int e = 1; e < E_; ++e) {
        float4 v = ((const float4*)P)[i + (size_t)e * ps4];
        s.x += v.x; s.y += v.y; s.z += v.z; s.w += v.w;
    }
    ((float4*)comb)[i] = s;
}

// ---------------- head ----------------
__global__ __launch_bounds__(256) void head_k(const float* __restrict__ comb,
                                              const float* __restrict__ Wh,
                                              const float* __restrict__ bh,
                                              float* __restrict__ out) {
    __shared__ float hs[8][512];
    int b0 = blockIdx.x * 8;
    for (int i = threadIdx.x; i < 8 * 128; i += 256) {
        int rr = i >> 7, cc = i & 127;
        ((float4*)hs[rr])[cc] = ((const float4*)(comb + (size_t)(b0 + rr) * 512))[cc];
    }
    __syncthreads();
    int r = threadIdx.x >> 5, c = threadIdx.x & 31;
    const float* wrow = Wh + (size_t)c * 512;
    float acc = 0.f;
    for (int k = 0; k < 512; k += 4) {
        float4 wv = *(const float4*)(wrow + k);
        float4 hv = *(const float4*)(&hs[r][k]);
        acc += hv.x * wv.x + hv.y * wv.y + hv.z * wv.z + hv.w * wv.w;
    }
    out[(size_t)(b0 + r) * 32 + c] = acc + bh[c];
}

// ---------------- launcher ----------------
extern "C" void kernel_launch(void* const* d_in, const int* in_sizes, int n_in,
                              void* d_out, int out_size, void* d_ws, size_t ws_size,
                              hipStream_t stream)
{
    const float* x      = (const float*)d_in[0];
    const float* lang   = (const float*)d_in[1];
    const float* h_r    = (const float*)d_in[2];
    const float* h_e    = (const float*)d_in[3];
    const float* W_in   = (const float*)d_in[4];
    const float* b_in   = (const float*)d_in[5];
    const float* Wih_r  = (const float*)d_in[6];
    const float* Whh_r  = (const float*)d_in[7];
    const float* bih_r  = (const float*)d_in[8];
    const float* bhh_r  = (const float*)d_in[9];
    const float* W_fc   = (const float*)d_in[10];
    const float* b_fc   = (const float*)d_in[11];
    const float* Wih_e  = (const float*)d_in[12];
    const float* Whh_e  = (const float*)d_in[13];
    const float* bih_e  = (const float*)d_in[14];
    const float* bhh_e  = (const float*)d_in[15];
    const float* W_proj = (const float*)d_in[16];
    const float* b_proj = (const float*)d_in[17];
    const float* W_head = (const float*)d_in[18];
    const float* b_head = (const float*)d_in[19];

    float* out_logits = (float*)d_out;                 // B*A
    float* out_hr     = out_logits + (size_t)B_ * A_;  // B*HR
    float* out_he     = out_hr + (size_t)B_ * HR_;     // E*B*H

    char* wsb = (char*)d_ws;
    size_t off = 0;
    auto alloc = [&](size_t bytes) -> char* {
        char* p = wsb + off;
        off = (off + bytes + 255) & ~(size_t)255;
        return p;
    };

    // ---- persistent (through expert loop): 63.0 MB ----
    __bf16* Wih_e_hl = (__bf16*)alloc((size_t)12288 * 1024 * 2);   // [hi|lo]
    __bf16* Whh_e_b  = (__bf16*)alloc((size_t)8 * 1536 * 512 * 2);
    __bf16* W_proj_b = (__bf16*)alloc((size_t)8 * 512 * 512 * 2);
    __bf16* xp_cat   = (__bf16*)alloc((size_t)B_ * 1536 * 2);      // [hi|hi|lo]
    float*  wts      = (float*)alloc((size_t)B_ * E_ * 4);
    float*  comb     = (float*)alloc((size_t)B_ * D_ * 4);

    // ---- region R: max(prep ~42 MB, chunk 67.1 MB) ----
    char* R = wsb + off;
    // prep-phase layout within R:
    __bf16* W_in_hl  = (__bf16*)(R);                                   // 512*1280*2  = 1.31 MB
    __bf16* Wih_r_hl = (__bf16*)(R + 1310720);                         // 768*1024*2  = 1.57 MB
    __bf16* Whh_r_b  = (__bf16*)(R + 1310720 + 1572864);               // 768*256*2   = 0.39 MB
    __bf16* hr_b     = (__bf16*)(R + 1310720 + 1572864 + 393216);      // B*256*2     = 2.10 MB
    char*   Rp       = R + 1310720 + 1572864 + 393216 + 2097152;
    __bf16* xcat_cat = (__bf16*)(Rp);                                  // B*1920*2    = 15.73 MB
    float*  xp       = (float*)(Rp + 15728640);                        // B*512*4     = 8.39 MB
    float*  gxr      = (float*)(Rp + 15728640 + 8388608);              // B*768*4     = 12.58 MB
    // chunk-phase layout within R (prep all dead by then), 2048-row super-chunks:
    float*  Pch      = (float*)(R);                                    // 8*2048*512*4 = 33.55 MB
    __bf16* hebch    = (__bf16*)(R + 33554432);                        // 8*2048*512*2 = 16.78 MB
    __bf16* henewch  = (__bf16*)(R + 33554432 + 16777216);             // 16.78 MB

    // ---- weight prep ----
    wcat2_k<<<(512 * 160 + 255) / 256, 256, 0, stream>>>(W_in, W_in_hl, 160, 512 * 160);
    wcat2_k<<<(768 * 128 + 255) / 256, 256, 0, stream>>>(Wih_r, Wih_r_hl, 128, 768 * 128);
    wcat2_k<<<(12288 * 128 + 255) / 256, 256, 0, stream>>>(Wih_e, Wih_e_hl, 128, 12288 * 128);
    f2b_k<<<(49152 + 255) / 256, 256, 0, stream>>>(Whh_r, Whh_r_b, 49152);
    f2b_k<<<(1572864 + 255) / 256, 256, 0, stream>>>(Whh_e, Whh_e_b, 1572864);
    f2b_k<<<(524288 + 255) / 256, 256, 0, stream>>>(W_proj, W_proj_b, 524288);
    f2b_k<<<(262144 + 255) / 256, 256, 0, stream>>>(h_r, hr_b, 262144);

    // ---- input projection (hi/lo accurate) ----
    concat_cat_k<<<(B_ * 160) / 256, 256, 0, stream>>>(x, lang, xcat_cat);
    mgemm<0, false><<<dim3(32, 4, 1), 256, 0, stream>>>(xcat_cat, 0, W_in_hl, 0, 1280, 1280,
                                                        b_in, 0, xp, 0, D_, 1920, nullptr, 0, 0);
    split2cat_k<<<(B_ * 128) / 256, 256, 0, stream>>>(xp, xp_cat);

    // ---- router: gx GEMM, fused gh+GRU, softmax ----
    mgemm<0, false><<<dim3(32, 6, 1), 256, 0, stream>>>(xp_cat, 0, Wih_r_hl, 0, 1024, 1024,
                                                        bih_r, 0, gxr, 0, 3 * HR_, 1536, nullptr, 0, 0);
    fgru<HR_, false, false><<<dim3(32, 4, 1), 256, 0, stream>>>(
        hr_b, 0, Whh_r_b, 0, bhh_r, 0, gxr, 0, h_r, 0, out_hr, 0, nullptr, 0);
    fc_softmax_k<<<B_ / 32, 256, 0, stream>>>(out_hr, W_fc, b_fc, wts);

    // ---- experts: 2 super-chunks of 2048 rows; gx+gh+GRU fused per chunk ----
    // Grids are (expert, ..): gridDim.x == 8 == #XCDs -> one expert per XCD.
    for (int c = 0; c < 2; ++c) {
        const int r0 = c * 2048;
        f2bhe_k<<<(8 * 2048 * 128) / 256, 256, 0, stream>>>(h_e, hebch, r0);
        // fused gx-GEMM + gh-GEMM + GRU -> out_he (fp32) + henew (bf16)
        fxgru_k<2048><<<dim3(8, 8, 16), 256, 0, stream>>>(
            xp_cat + (size_t)r0 * 1536,
            Wih_e_hl, bih_e,
            hebch, Whh_e_b, bhh_e,
            h_e + (size_t)r0 * H_, (long long)B_ * H_,
            out_he + (size_t)r0 * H_, (long long)B_ * H_,
            henewch);
        // weighted projection into P planes
        mgemm<2, true><<<dim3(8, 4, 16), 256, 0, stream>>>(
            henewch, (long long)2048 * H_,
            W_proj_b, (long long)D_ * H_, 512, 512,
            b_proj, D_,
            Pch, (long long)2048 * D_, D_, H_,
            wts + (size_t)r0 * E_, E_, 1);
        reduce8_k<<<(2048 * 128 + 255) / 256, 256, 0, stream>>>(
            Pch, comb + (size_t)r0 * D_, 2048 * 128, 2048 * 128);
    }

    // ---- head ----
    head_k<<<B_ / 8, 256, 0, stream>>>(comb, W_head, b_head, out_logits);
}

// Round 8
// 672.371 us; speedup vs baseline: 1.1869x; 1.1869x over previous
//
#include <hip/hip_runtime.h>
#include <cstddef>
#include <cstdint>

// Problem constants
#define B_  4096
#define I_  512
#define L_  128
#define D_  512
#define E_  8
#define H_  512
#define HR_ 256
#define A_  32

typedef __attribute__((ext_vector_type(8))) __bf16 bf16x8;
typedef __attribute__((ext_vector_type(4))) __bf16 bf16x4;
typedef __attribute__((ext_vector_type(4))) float floatx4;

__device__ __forceinline__ float sigmoidf_(float x) { return 1.0f / (1.0f + __expf(-x)); }

__device__ __forceinline__ void load_lds16(const void* g, void* l) {
    __builtin_amdgcn_global_load_lds((__attribute__((address_space(1))) void*)g,
                                     (__attribute__((address_space(3))) void*)l, 16, 0, 0);
}

struct HiLo { __bf16 h, l; };
__device__ __forceinline__ HiLo hi_lo(float v) {
    HiLo r;
    r.h = (__bf16)v;
    r.l = (__bf16)(v - (float)r.h);
    return r;
}
__device__ __forceinline__ void split4(float4 v, bf16x4& hi, bf16x4& lo) {
    HiLo a = hi_lo(v.x), b = hi_lo(v.y), c = hi_lo(v.z), d = hi_lo(v.w);
    hi = (bf16x4){a.h, b.h, c.h, d.h};
    lo = (bf16x4){a.l, b.l, c.l, d.l};
}

// =====================================================================
// LDS subtile swizzle (all MFMA kernels): each global_load_lds writes one
// 1024-B subtile = 16 rows x 4 segs (of 8 bf16 = 16 B). Slot s (= staging
// lane) holds (row = s>>2, seg = (s&3) ^ ((s>>3)&3)).
//  - STAGING: lane L fetches row L>>2, seg (L&3)^((L>>3)&3): the 4 lanes of
//    a row fetch the SAME 64-B chunk (permuted order) -> coalescing = r6.
//  - READ: lane L needs (row r=L&15, seg q=L>>4) -> slot r*4 + (q^((r>>1)&3)).
//    Slot-mod-8 over lanes 0-15: 0,4,1,5,2,6,3,7,... each 4-bank group 2x =
//    the structural minimum, free on CDNA4 (vs 8-way, 10.5M conflict cyc, in
//    the plain row-major layout; vs r7's scattered-source linear layout which
//    was conflict-free but broke staging coalescing -> 224us).
// =====================================================================
__device__ __forceinline__ int stage_seg(int lane) {
    return (lane & 3) ^ ((lane >> 3) & 3);
}
__device__ __forceinline__ int frag_off(int lane) {      // elements within subtile
    const int r = lane & 15, q = lane >> 4;
    return (r * 4 + (q ^ ((r >> 1) & 3))) * 8;
}

// ---------------- conversion kernels ----------------
__global__ __launch_bounds__(256) void f2b_k(const float* __restrict__ src,
                                             __bf16* __restrict__ dst, int n4) {
    int i = blockIdx.x * 256 + threadIdx.x;
    if (i < n4) {
        float4 v = ((const float4*)src)[i];
        bf16x4 o = { (__bf16)v.x, (__bf16)v.y, (__bf16)v.z, (__bf16)v.w };
        *(bf16x4*)(dst + (size_t)i * 4) = o;
    }
}

// W (N,K) fp32 -> out (N,2K) bf16 = [W_hi | W_lo] per row
__global__ __launch_bounds__(256) void wcat2_k(const float* __restrict__ W,
                                               __bf16* __restrict__ out,
                                               int K4, int n4tot) {
    int i4 = blockIdx.x * 256 + threadIdx.x;
    if (i4 >= n4tot) return;
    int row = i4 / K4;
    int c4  = i4 - row * K4;
    const int K = K4 * 4;
    float4 v = ((const float4*)W)[i4];
    bf16x4 hi, lo;
    split4(v, hi, lo);
    __bf16* dst = out + (size_t)row * 2 * K + c4 * 4;
    *(bf16x4*)(dst)     = hi;
    *(bf16x4*)(dst + K) = lo;
}

// [x (B,512) | lang (B,128)] -> xcat (B,1920) = [hi | hi | lo]
__global__ __launch_bounds__(256) void concat_cat_k(const float* __restrict__ x,
                                                    const float* __restrict__ lang,
                                                    __bf16* __restrict__ out) {
    int idx = blockIdx.x * 256 + threadIdx.x;   // over B_*160 float4 groups
    int b = idx / 160;
    int c = idx - b * 160;
    float4 v;
    if (c < 128) v = ((const float4*)x)[(size_t)b * 128 + c];
    else         v = ((const float4*)lang)[(size_t)b * 32 + (c - 128)];
    bf16x4 hi, lo;
    split4(v, hi, lo);
    __bf16* dst = out + (size_t)b * 1920 + c * 4;
    *(bf16x4*)(dst)        = hi;
    *(bf16x4*)(dst + 640)  = hi;
    *(bf16x4*)(dst + 1280) = lo;
}

// xp fp32 (B,512) -> xp_cat (B,1536) = [hi | hi | lo]
__global__ __launch_bounds__(256) void split2cat_k(const float* __restrict__ src,
                                                   __bf16* __restrict__ out) {
    int i4 = blockIdx.x * 256 + threadIdx.x;    // over B_*128
    int b = i4 >> 7;
    int c4 = i4 & 127;
    float4 v = ((const float4*)src)[i4];
    bf16x4 hi, lo;
    split4(v, hi, lo);
    __bf16* dst = out + (size_t)b * 1536 + c4 * 4;
    *(bf16x4*)(dst)         = hi;
    *(bf16x4*)(dst + 512)   = hi;
    *(bf16x4*)(dst + 1024)  = lo;
}

// h_e chunk convert: (E, B, H) fp32 rows [r0, r0+2048) -> (E, 2048, H) bf16
__global__ __launch_bounds__(256) void f2bhe_k(const float* __restrict__ he,
                                               __bf16* __restrict__ dst, int r0) {
    int i4 = blockIdx.x * 256 + threadIdx.x;    // over 8*2048*128
    int e   = i4 >> 18;
    int rem = i4 & 262143;
    int row = rem >> 7;
    int c4  = rem & 127;
    float4 v = ((const float4*)he)[(size_t)e * (B_ * 128) + (size_t)(r0 + row) * 128 + c4];
    bf16x4 o = { (__bf16)v.x, (__bf16)v.y, (__bf16)v.z, (__bf16)v.w };
    *(bf16x4*)(dst + (size_t)i4 * 4) = o;
}

// ---------------- MFMA GEMM (2-phase dbuf, XOR-swizzled subtiles) ----------
template<int MODE, bool XORD>
__global__ __launch_bounds__(256) void mgemm(
    const __bf16* __restrict__ A, long long aBatch,
    const __bf16* __restrict__ Bw, long long bBatch, int bRS, int kWrap,
    const float* __restrict__ bias, long long biasBatch,
    float* __restrict__ Cv, long long cBatch,
    int N, int K,
    const float* __restrict__ scale, int sstride, int szBatch)
{
    constexpr int ASZ = 128 * 32;
    __shared__ __align__(16) __bf16 As[2 * ASZ];
    __shared__ __align__(16) __bf16 Bs[2 * ASZ];

    const int tid  = threadIdx.x;
    const int w    = tid >> 6;
    const int lane = tid & 63;
    const int m0 = (XORD ? blockIdx.z : blockIdx.x) * 128;
    const int n0 = blockIdx.y * 128;
    const int z  = XORD ? blockIdx.x : blockIdx.z;

    // staging: row = lane>>2 (4-lane groups share a 64-B chunk), seg XOR'd
    const int lrow = lane >> 2;
    const int lsegx = stage_seg(lane);
    const __bf16* Ag0 = A + (size_t)z * aBatch + (size_t)(m0 + w * 32 + lrow) * K + lsegx * 8;
    const __bf16* Ag1 = Ag0 + (size_t)16 * K;
    const __bf16* Bg0 = Bw + (size_t)z * bBatch + (size_t)(n0 + w * 32 + lrow) * bRS + lsegx * 8;
    const __bf16* Bg1 = Bg0 + (size_t)16 * bRS;

    const int wm = w & 1, wn = w >> 1;
    const int lr16 = lane & 15;
    const int lq   = lane >> 4;
    const int fro  = frag_off(lane);

    floatx4 acc[4][4];
#pragma unroll
    for (int i = 0; i < 4; ++i)
#pragma unroll
        for (int j = 0; j < 4; ++j) acc[i][j] = (floatx4){0.f, 0.f, 0.f, 0.f};

    const int NSTEP = K >> 5;

    auto STAGE = [&](int s, int buf) {
        const int k0 = s << 5;
        const int kb = (k0 < kWrap) ? k0 : (k0 - kWrap);
        __bf16* al = As + buf * ASZ + (w * 32) * 32;
        __bf16* bl = Bs + buf * ASZ + (w * 32) * 32;
        load_lds16(Ag0 + k0, al);
        load_lds16(Ag1 + k0, al + 16 * 32);
        load_lds16(Bg0 + kb, bl);
        load_lds16(Bg1 + kb, bl + 16 * 32);
    };

    int cur = 0;
    STAGE(0, 0);
    __syncthreads();
    for (int s = 0; s < NSTEP; ++s) {
        if (s + 1 < NSTEP) STAGE(s + 1, cur ^ 1);

        const __bf16* Af = As + cur * ASZ + wm * 2048 + fro;
        const __bf16* Bf = Bs + cur * ASZ + wn * 2048 + fro;
        bf16x8 af[4], bfr[4];
#pragma unroll
        for (int t = 0; t < 4; ++t) {
            af[t]  = *(const bf16x8*)(Af + t * 512);
            bfr[t] = *(const bf16x8*)(Bf + t * 512);
        }
#pragma unroll
        for (int tm = 0; tm < 4; ++tm)
#pragma unroll
            for (int tn = 0; tn < 4; ++tn)
                acc[tm][tn] = __builtin_amdgcn_mfma_f32_16x16x32_bf16(af[tm], bfr[tn], acc[tm][tn], 0, 0, 0);

        __syncthreads();
        cur ^= 1;
    }

    const float* biasz = bias + (size_t)z * biasBatch;
    const int sz = z * szBatch;
#pragma unroll
    for (int tm = 0; tm < 4; ++tm) {
        const int mbase = m0 + wm * 64 + tm * 16 + lq * 4;
#pragma unroll
        for (int r = 0; r < 4; ++r) {
            const int m = mbase + r;
            float wsc = 0.f;
            if (MODE == 2) wsc = scale[(size_t)m * sstride + sz];
#pragma unroll
            for (int tn = 0; tn < 4; ++tn) {
                const int n = n0 + wn * 64 + tn * 16 + lr16;
                float v = acc[tm][tn][r] + biasz[n];
                const size_t ci = (size_t)z * cBatch + (size_t)m * N + n;
                if (MODE == 0) Cv[ci] = v;
                else           Cv[ci] = wsc * v;
            }
        }
    }
}

// ---------------- router fused gh-GEMM + GRU (XOR-swizzled subtiles) ---------
template<int HD, bool WRITE_HNEW, bool XORD>
__global__ __launch_bounds__(256) void fgru(
    const __bf16* __restrict__ Ab, long long aBatch,     // (z, Mtot, HD) bf16
    const __bf16* __restrict__ Whh, long long wBatch,    // (z, 3HD, HD) bf16
    const float* __restrict__ bhh, long long bhhBatch,   // (z, 3HD)
    const float* __restrict__ gx, long long gxBatch,     // (z, Mtot, 3HD) fp32
    const float* __restrict__ hprev, long long hBatch,   // (z, ..., HD) fp32
    float* __restrict__ hout, long long hoBatch,         // fp32
    __bf16* __restrict__ hnew, long long hnBatch)        // bf16
{
    __shared__ __align__(16) __bf16 As[128 * 32];
    __shared__ __align__(16) __bf16 Bs[192 * 32];

    const int tid  = threadIdx.x;
    const int w    = tid >> 6;
    const int lane = tid & 63;
    const int m0 = (XORD ? blockIdx.z : blockIdx.x) * 128;
    const int j0 = blockIdx.y * 64;
    const int z  = XORD ? blockIdx.x : blockIdx.z;

    const int lrow = lane >> 2;
    const int lsegx = stage_seg(lane);
    const __bf16* Ag0 = Ab + (size_t)z * aBatch + (size_t)(m0 + w * 32 + lrow) * HD + lsegx * 8;
    const __bf16* Ag1 = Ag0 + (size_t)16 * HD;
    __bf16* Al0 = As + (w * 32) * 32;
    __bf16* Al1 = Al0 + 16 * 32;

    const __bf16* Wz = Whh + (size_t)z * wBatch;
    const __bf16* Bg[3];
    __bf16* Bl[3];
#pragma unroll
    for (int i = 0; i < 3; ++i) {
        const int r = (w * 3 + i) * 16 + lrow;          // 0..191
        const int gate = r >> 6;
        const int grow = gate * HD + j0 + (r & 63);
        Bg[i] = Wz + (size_t)grow * HD + lsegx * 8;
        Bl[i] = Bs + ((w * 3 + i) * 16) * 32;
    }

    const int mh = w & 1, nh = w >> 1;
    const int lr16 = lane & 15;
    const int lq   = lane >> 4;
    const int fro  = frag_off(lane);
    const __bf16* Af = As + mh * 2048 + fro;
    const __bf16* Bf = Bs + nh * 1024 + fro;

    floatx4 acc[3][4][2];
#pragma unroll
    for (int g = 0; g < 3; ++g)
#pragma unroll
        for (int i = 0; i < 4; ++i)
#pragma unroll
            for (int j = 0; j < 2; ++j) acc[g][i][j] = (floatx4){0.f, 0.f, 0.f, 0.f};

    for (int k0 = 0; k0 < HD; k0 += 32) {
        __syncthreads();
        load_lds16(Ag0 + k0, Al0);
        load_lds16(Ag1 + k0, Al1);
#pragma unroll
        for (int i = 0; i < 3; ++i) load_lds16(Bg[i] + k0, Bl[i]);
        __syncthreads();

        bf16x8 af[4], bf[3][2];
#pragma unroll
        for (int t = 0; t < 4; ++t) af[t] = *(const bf16x8*)(Af + t * 512);
#pragma unroll
        for (int g = 0; g < 3; ++g)
#pragma unroll
            for (int tn = 0; tn < 2; ++tn)
                bf[g][tn] = *(const bf16x8*)(Bf + (g * 4 + tn) * 512);
#pragma unroll
        for (int g = 0; g < 3; ++g)
#pragma unroll
            for (int tm = 0; tm < 4; ++tm)
#pragma unroll
                for (int tn = 0; tn < 2; ++tn)
                    acc[g][tm][tn] = __builtin_amdgcn_mfma_f32_16x16x32_bf16(af[tm], bf[g][tn], acc[g][tm][tn], 0, 0, 0);
    }

    const float* bhhz = bhh + (size_t)z * bhhBatch;
#pragma unroll
    for (int tm = 0; tm < 4; ++tm) {
#pragma unroll
        for (int rr = 0; rr < 4; ++rr) {
            const int row = m0 + mh * 64 + tm * 16 + lq * 4 + rr;
            const float* gxrow = gx + (size_t)z * gxBatch + (size_t)row * (3 * HD);
            const float* hrow  = hprev + (size_t)z * hBatch + (size_t)row * HD;
#pragma unroll
            for (int tn = 0; tn < 2; ++tn) {
                const int j = j0 + nh * 32 + tn * 16 + lr16;
                float ghr = acc[0][tm][tn][rr] + bhhz[j];
                float ghz = acc[1][tm][tn][rr] + bhhz[HD + j];
                float ghn = acc[2][tm][tn][rr] + bhhz[2 * HD + j];
                float r  = sigmoidf_(gxrow[j] + ghr);
                float zz = sigmoidf_(gxrow[HD + j] + ghz);
                float n  = tanhf(gxrow[2 * HD + j] + r * ghn);
                float hv = hrow[j];
                float o  = (1.f - zz) * n + zz * hv;
                hout[(size_t)z * hoBatch + (size_t)row * HD + j] = o;
                if (WRITE_HNEW)
                    hnew[(size_t)z * hnBatch + (size_t)row * HD + j] = (__bf16)o;
            }
        }
    }
}

// ---------------- fused expert gx+gh GEMM + GRU (depth-3 + XOR swizzle) ------
template<int MROWS>
__global__ __launch_bounds__(256, 2) void fxgru_k(
    const __bf16* __restrict__ xpc,     // (MROWS, 1536) chunk [hi|hi|lo]
    const __bf16* __restrict__ Wih,     // (E, 1536, 1024) rows [hi|lo]
    const float* __restrict__ bih,      // (E, 1536)
    const __bf16* __restrict__ heb,     // (E, MROWS, 512) bf16 h_prev chunk
    const __bf16* __restrict__ Whh,     // (E, 1536, 512) bf16
    const float* __restrict__ bhh,      // (E, 1536)
    const float* __restrict__ hprev,    // (E, B, 512) fp32, chunk base
    long long hBatch,
    float* __restrict__ hout,           // (E, B, 512) fp32, chunk base
    long long hoBatch,
    __bf16* __restrict__ hnew)          // (E, MROWS, 512) bf16
{
    constexpr int ASZ = 128 * 32;
    constexpr int BSZ = 192 * 32;
    __shared__ __align__(16) __bf16 As[3 * ASZ];   // 24 KB
    __shared__ __align__(16) __bf16 Bs[3 * BSZ];   // 36 KB  (total 60 KB, 2 blk/CU)

    const int tid  = threadIdx.x;
    const int w    = tid >> 6;
    const int lane = tid & 63;
    const int z  = blockIdx.x;          // expert -> XCD
    const int j0 = blockIdx.y * 64;
    const int m0 = blockIdx.z * 128;

    const int lrow = lane >> 2;         // staging row (coalesced 64-B chunks)
    const int lsegx = stage_seg(lane);  // XOR'd segment
    const int aoff = (w * 32) * 32;
    int BlOff[3];
#pragma unroll
    for (int i = 0; i < 3; ++i) BlOff[i] = ((w * 3 + i) * 16) * 32;

    const int mh = w & 1, nh = w >> 1;
    const int lr16 = lane & 15;
    const int lq   = lane >> 4;
    const int fro  = frag_off(lane);

    floatx4 acc[3][4][2];   // gate r/z: gx+gh summed in place; gate n: gx only
    floatx4 accn[4][2];     // gh n-gate (kept separate for r*gh_n)
#pragma unroll
    for (int g = 0; g < 3; ++g)
#pragma unroll
        for (int i = 0; i < 4; ++i)
#pragma unroll
            for (int j = 0; j < 2; ++j) acc[g][i][j] = (floatx4){0.f, 0.f, 0.f, 0.f};
#pragma unroll
    for (int i = 0; i < 4; ++i)
#pragma unroll
        for (int j = 0; j < 2; ++j) accn[i][j] = (floatx4){0.f, 0.f, 0.f, 0.f};

    auto COMPA = [&](int buf) {
        const __bf16* Af = As + buf * ASZ + mh * 2048 + fro;
        const __bf16* Bf = Bs + buf * BSZ + nh * 1024 + fro;
        bf16x8 af[4], bf[3][2];
#pragma unroll
        for (int t = 0; t < 4; ++t) af[t] = *(const bf16x8*)(Af + t * 512);
#pragma unroll
        for (int g = 0; g < 3; ++g)
#pragma unroll
            for (int tn = 0; tn < 2; ++tn)
                bf[g][tn] = *(const bf16x8*)(Bf + (g * 4 + tn) * 512);
#pragma unroll
        for (int g = 0; g < 3; ++g)
#pragma unroll
            for (int tm = 0; tm < 4; ++tm)
#pragma unroll
                for (int tn = 0; tn < 2; ++tn)
                    acc[g][tm][tn] = __builtin_amdgcn_mfma_f32_16x16x32_bf16(af[tm], bf[g][tn], acc[g][tm][tn], 0, 0, 0);
    };
    auto COMPB = [&](int buf) {
        const __bf16* Af = As + buf * ASZ + mh * 2048 + fro;
        const __bf16* Bf = Bs + buf * BSZ + nh * 1024 + fro;
        bf16x8 af[4], bf[3][2];
#pragma unroll
        for (int t = 0; t < 4; ++t) af[t] = *(const bf16x8*)(Af + t * 512);
#pragma unroll
        for (int g = 0; g < 3; ++g)
#pragma unroll
            for (int tn = 0; tn < 2; ++tn)
                bf[g][tn] = *(const bf16x8*)(Bf + (g * 4 + tn) * 512);
#pragma unroll
        for (int tm = 0; tm < 4; ++tm)
#pragma unroll
            for (int tn = 0; tn < 2; ++tn) {
                acc[0][tm][tn] = __builtin_amdgcn_mfma_f32_16x16x32_bf16(af[tm], bf[0][tn], acc[0][tm][tn], 0, 0, 0);
                acc[1][tm][tn] = __builtin_amdgcn_mfma_f32_16x16x32_bf16(af[tm], bf[1][tn], acc[1][tm][tn], 0, 0, 0);
                accn[tm][tn]   = __builtin_amdgcn_mfma_f32_16x16x32_bf16(af[tm], bf[2][tn], accn[tm][tn], 0, 0, 0);
            }
    };

    // wait for own tile-loads (leave N in flight) then workgroup barrier
#define TILE_WAIT(N) do { \
        asm volatile("s_waitcnt vmcnt(" #N ")" ::: "memory"); \
        __builtin_amdgcn_s_barrier(); \
        __builtin_amdgcn_sched_barrier(0); \
    } while (0)
#define READ_DONE() do { \
        __builtin_amdgcn_sched_barrier(0); \
        __builtin_amdgcn_s_barrier(); \
    } while (0)

    int cur = 0;
    // ================= phase A: gx, tiles 0..47 =================
    {
        const __bf16* AgA0 = xpc + (size_t)(m0 + w * 32 + lrow) * 1536 + lsegx * 8;
        const __bf16* AgA1 = AgA0 + (size_t)16 * 1536;
        const __bf16* WihZ = Wih + (size_t)z * (1536 * 1024);
        const __bf16* BgA[3];
#pragma unroll
        for (int i = 0; i < 3; ++i) {
            const int r = (w * 3 + i) * 16 + lrow;          // 0..191
            const int grow = (r >> 6) * 512 + j0 + (r & 63);
            BgA[i] = WihZ + (size_t)grow * 1024 + lsegx * 8;
        }
        auto STAGE_A = [&](int s, int buf) {
            const int k0 = s << 5;
            const int kb = (k0 < 1024) ? k0 : (k0 - 1024);
            __bf16* al = As + buf * ASZ + aoff;
            __bf16* bl = Bs + buf * BSZ;
            load_lds16(AgA0 + k0, al);
            load_lds16(AgA1 + k0, al + 16 * 32);
#pragma unroll
            for (int i = 0; i < 3; ++i) load_lds16(BgA[i] + kb, bl + BlOff[i]);
        };

        STAGE_A(0, 0);
        STAGE_A(1, 1);
        STAGE_A(2, 2);                    // 15 loads in flight
        for (int s = 0; s < 45; ++s) {    // tiles 0..44; stage tiles 3..47
            TILE_WAIT(10);
            COMPA(cur);
            READ_DONE();
            STAGE_A(s + 3, cur);
            cur = (cur == 2) ? 0 : cur + 1;
        }
    }
    // ================= boundary: finish A tiles 45..47, stage B 0..2 =========
    {
        const __bf16* AgB0 = heb + (size_t)z * (MROWS * 512)
                                 + (size_t)(m0 + w * 32 + lrow) * 512 + lsegx * 8;
        const __bf16* AgB1 = AgB0 + (size_t)16 * 512;
        const __bf16* WhhZ = Whh + (size_t)z * (1536 * 512);
        const __bf16* BgB[3];
#pragma unroll
        for (int i = 0; i < 3; ++i) {
            const int r = (w * 3 + i) * 16 + lrow;
            const int grow = (r >> 6) * 512 + j0 + (r & 63);
            BgB[i] = WhhZ + (size_t)grow * 512 + lsegx * 8;
        }
        auto STAGE_B = [&](int t, int buf) {
            const int k0 = t << 5;
            __bf16* al = As + buf * ASZ + aoff;
            __bf16* bl = Bs + buf * BSZ;
            load_lds16(AgB0 + k0, al);
            load_lds16(AgB1 + k0, al + 16 * 32);
#pragma unroll
            for (int i = 0; i < 3; ++i) load_lds16(BgB[i] + k0, bl + BlOff[i]);
        };

#pragma unroll
        for (int q = 0; q < 3; ++q) {     // A tiles 45,46,47; stage B 0,1,2
            TILE_WAIT(10);
            COMPA(cur);
            READ_DONE();
            STAGE_B(q, cur);
            cur = (cur == 2) ? 0 : cur + 1;
        }
        // ================= phase B: gh, tiles 0..15 =================
        for (int t = 0; t < 13; ++t) {    // stage tiles 3..15
            TILE_WAIT(10);
            COMPB(cur);
            READ_DONE();
            STAGE_B(t + 3, cur);
            cur = (cur == 2) ? 0 : cur + 1;
        }
        TILE_WAIT(10);                    // tile 13 (14,15 in flight)
        COMPB(cur);
        cur = (cur == 2) ? 0 : cur + 1;
        TILE_WAIT(5);                     // tile 14
        COMPB(cur);
        cur = (cur == 2) ? 0 : cur + 1;
        TILE_WAIT(0);                     // tile 15
        COMPB(cur);
    }
#undef TILE_WAIT
#undef READ_DONE

    // ---- GRU epilogue ----
    const float* bihz = bih + (size_t)z * 1536;
    const float* bhhz = bhh + (size_t)z * 1536;
#pragma unroll
    for (int tm = 0; tm < 4; ++tm) {
#pragma unroll
        for (int rr = 0; rr < 4; ++rr) {
            const int row = m0 + mh * 64 + tm * 16 + lq * 4 + rr;
            const float* hrow = hprev + (size_t)z * hBatch + (size_t)row * 512;
#pragma unroll
            for (int tn = 0; tn < 2; ++tn) {
                const int j = j0 + nh * 32 + tn * 16 + lr16;
                float gr  = acc[0][tm][tn][rr] + bihz[j] + bhhz[j];
                float gz  = acc[1][tm][tn][rr] + bihz[512 + j] + bhhz[512 + j];
                float gxn = acc[2][tm][tn][rr] + bihz[1024 + j];
                float ghn = accn[tm][tn][rr] + bhhz[1024 + j];
                float r  = sigmoidf_(gr);
                float zz = sigmoidf_(gz);
                float n  = tanhf(gxn + r * ghn);
                float hv = hrow[j];
                float o  = (1.f - zz) * n + zz * hv;
                hout[(size_t)z * hoBatch + (size_t)row * 512 + j] = o;
                hnew[(size_t)z * (MROWS * 512) + (size_t)row * 512 + j] = (__bf16)o;
            }
        }
    }
}

// ---------------- router fc + softmax ----------------
__global__ __launch_bounds__(256) void fc_softmax_k(const float* __restrict__ hr,
                                                    const float* __restrict__ Wfc,
                                                    const float* __restrict__ bfc,
                                                    float* __restrict__ wts) {
    int lane = threadIdx.x & 63;
    int wave = threadIdx.x >> 6;
    int rg = lane >> 3;
    int e  = lane & 7;
    int b  = blockIdx.x * 32 + wave * 8 + rg;
    const float* h = hr + (size_t)b * HR_;
    const float* w = Wfc + (size_t)e * HR_;
    float acc = 0.0f;
#pragma unroll 4
    for (int k = 0; k < HR_; k += 4) {
        float4 hv = *(const float4*)(h + k);
        float4 wv = *(const float4*)(w + k);
        acc += hv.x * wv.x + hv.y * wv.y + hv.z * wv.z + hv.w * wv.w;
    }
    acc += bfc[e];
    float m = acc;
    for (int off = 4; off; off >>= 1) m = fmaxf(m, __shfl_xor(m, off, 8));
    float ex = __expf(acc - m);
    float s = ex;
    for (int off = 4; off; off >>= 1) s += __shfl_xor(s, off, 8);
    wts[(size_t)b * E_ + e] = ex / s;
}

// ---------------- reduce 8 expert P planes (chunk) -> comb ----------------
__global__ __launch_bounds__(256) void reduce8_k(const float* __restrict__ P,
                                                 float* __restrict__ comb,
                                                 int n4, int ps4) {
    int i = blockIdx.x * 256 + threadIdx.x;
    if (i >= n4) return;
    float4 s = ((const float4*)P)[i];
#pragma unroll
    for (int e = 1; e < E_; ++e) {
        float4 v = ((const float4*)P)[i + (size_t)e * ps4];
        s.x += v.x; s.y += v.y; s.z += v.z; s.w += v.w;
    }
    ((float4*)comb)[i] = s;
}

// ---------------- head ----------------
__global__ __launch_bounds__(256) void head_k(const float* __restrict__ comb,
                                              const float* __restrict__ Wh,
                                              const float* __restrict__ bh,
                                              float* __restrict__ out) {
    __shared__ float hs[8][512];
    int b0 = blockIdx.x * 8;
    for (int i = threadIdx.x; i < 8 * 128; i += 256) {
        int rr = i >> 7, cc = i & 127;
        ((float4*)hs[rr])[cc] = ((const float4*)(comb + (size_t)(b0 + rr) * 512))[cc];
    }
    __syncthreads();
    int r = threadIdx.x >> 5, c = threadIdx.x & 31;
    const float* wrow = Wh + (size_t)c * 512;
    float acc = 0.f;
    for (int k = 0; k < 512; k += 4) {
        float4 wv = *(const float4*)(wrow + k);
        float4 hv = *(const float4*)(&hs[r][k]);
        acc += hv.x * wv.x + hv.y * wv.y + hv.z * wv.z + hv.w * wv.w;
    }
    out[(size_t)(b0 + r) * 32 + c] = acc + bh[c];
}

// ---------------- launcher ----------------
extern "C" void kernel_launch(void* const* d_in, const int* in_sizes, int n_in,
                              void* d_out, int out_size, void* d_ws, size_t ws_size,
                              hipStream_t stream)
{
    const float* x      = (const float*)d_in[0];
    const float* lang   = (const float*)d_in[1];
    const float* h_r    = (const float*)d_in[2];
    const float* h_e    = (const float*)d_in[3];
    const float* W_in   = (const float*)d_in[4];
    const float* b_in   = (const float*)d_in[5];
    const float* Wih_r  = (const float*)d_in[6];
    const float* Whh_r  = (const float*)d_in[7];
    const float* bih_r  = (const float*)d_in[8];
    const float* bhh_r  = (const float*)d_in[9];
    const float* W_fc   = (const float*)d_in[10];
    const float* b_fc   = (const float*)d_in[11];
    const float* Wih_e  = (const float*)d_in[12];
    const float* Whh_e  = (const float*)d_in[13];
    const float* bih_e  = (const float*)d_in[14];
    const float* bhh_e  = (const float*)d_in[15];
    const float* W_proj = (const float*)d_in[16];
    const float* b_proj = (const float*)d_in[17];
    const float* W_head = (const float*)d_in[18];
    const float* b_head = (const float*)d_in[19];

    float* out_logits = (float*)d_out;                 // B*A
    float* out_hr     = out_logits + (size_t)B_ * A_;  // B*HR
    float* out_he     = out_hr + (size_t)B_ * HR_;     // E*B*H

    char* wsb = (char*)d_ws;
    size_t off = 0;
    auto alloc = [&](size_t bytes) -> char* {
        char* p = wsb + off;
        off = (off + bytes + 255) & ~(size_t)255;
        return p;
    };

    // ---- persistent (through expert loop): 63.0 MB ----
    __bf16* Wih_e_hl = (__bf16*)alloc((size_t)12288 * 1024 * 2);   // [hi|lo]
    __bf16* Whh_e_b  = (__bf16*)alloc((size_t)8 * 1536 * 512 * 2);
    __bf16* W_proj_b = (__bf16*)alloc((size_t)8 * 512 * 512 * 2);
    __bf16* xp_cat   = (__bf16*)alloc((size_t)B_ * 1536 * 2);      // [hi|hi|lo]
    float*  wts      = (float*)alloc((size_t)B_ * E_ * 4);
    float*  comb     = (float*)alloc((size_t)B_ * D_ * 4);

    // ---- region R: max(prep ~42 MB, chunk 67.1 MB) ----
    char* R = wsb + off;
    // prep-phase layout within R:
    __bf16* W_in_hl  = (__bf16*)(R);                                   // 512*1280*2  = 1.31 MB
    __bf16* Wih_r_hl = (__bf16*)(R + 1310720);                         // 768*1024*2  = 1.57 MB
    __bf16* Whh_r_b  = (__bf16*)(R + 1310720 + 1572864);               // 768*256*2   = 0.39 MB
    __bf16* hr_b     = (__bf16*)(R + 1310720 + 1572864 + 393216);      // B*256*2     = 2.10 MB
    char*   Rp       = R + 1310720 + 1572864 + 393216 + 2097152;
    __bf16* xcat_cat = (__bf16*)(Rp);                                  // B*1920*2    = 15.73 MB
    float*  xp       = (float*)(Rp + 15728640);                        // B*512*4     = 8.39 MB
    float*  gxr      = (float*)(Rp + 15728640 + 8388608);              // B*768*4     = 12.58 MB
    // chunk-phase layout within R (prep all dead by then), 2048-row super-chunks:
    float*  Pch      = (float*)(R);                                    // 8*2048*512*4 = 33.55 MB
    __bf16* hebch    = (__bf16*)(R + 33554432);                        // 8*2048*512*2 = 16.78 MB
    __bf16* henewch  = (__bf16*)(R + 33554432 + 16777216);             // 16.78 MB

    // ---- weight prep ----
    wcat2_k<<<(512 * 160 + 255) / 256, 256, 0, stream>>>(W_in, W_in_hl, 160, 512 * 160);
    wcat2_k<<<(768 * 128 + 255) / 256, 256, 0, stream>>>(Wih_r, Wih_r_hl, 128, 768 * 128);
    wcat2_k<<<(12288 * 128 + 255) / 256, 256, 0, stream>>>(Wih_e, Wih_e_hl, 128, 12288 * 128);
    f2b_k<<<(49152 + 255) / 256, 256, 0, stream>>>(Whh_r, Whh_r_b, 49152);
    f2b_k<<<(1572864 + 255) / 256, 256, 0, stream>>>(Whh_e, Whh_e_b, 1572864);
    f2b_k<<<(524288 + 255) / 256, 256, 0, stream>>>(W_proj, W_proj_b, 524288);
    f2b_k<<<(262144 + 255) / 256, 256, 0, stream>>>(h_r, hr_b, 262144);

    // ---- input projection (hi/lo accurate) ----
    concat_cat_k<<<(B_ * 160) / 256, 256, 0, stream>>>(x, lang, xcat_cat);
    mgemm<0, false><<<dim3(32, 4, 1), 256, 0, stream>>>(xcat_cat, 0, W_in_hl, 0, 1280, 1280,
                                                        b_in, 0, xp, 0, D_, 1920, nullptr, 0, 0);
    split2cat_k<<<(B_ * 128) / 256, 256, 0, stream>>>(xp, xp_cat);

    // ---- router: gx GEMM, fused gh+GRU, softmax ----
    mgemm<0, false><<<dim3(32, 6, 1), 256, 0, stream>>>(xp_cat, 0, Wih_r_hl, 0, 1024, 1024,
                                                        bih_r, 0, gxr, 0, 3 * HR_, 1536, nullptr, 0, 0);
    fgru<HR_, false, false><<<dim3(32, 4, 1), 256, 0, stream>>>(
        hr_b, 0, Whh_r_b, 0, bhh_r, 0, gxr, 0, h_r, 0, out_hr, 0, nullptr, 0);
    fc_softmax_k<<<B_ / 32, 256, 0, stream>>>(out_hr, W_fc, b_fc, wts);

    // ---- experts: 2 super-chunks of 2048 rows; gx+gh+GRU fused per chunk ----
    // Grids are (expert, ..): gridDim.x == 8 == #XCDs -> one expert per XCD.
    for (int c = 0; c < 2; ++c) {
        const int r0 = c * 2048;
        f2bhe_k<<<(8 * 2048 * 128) / 256, 256, 0, stream>>>(h_e, hebch, r0);
        // fused gx-GEMM + gh-GEMM + GRU -> out_he (fp32) + henew (bf16)
        fxgru_k<2048><<<dim3(8, 8, 16), 256, 0, stream>>>(
            xp_cat + (size_t)r0 * 1536,
            Wih_e_hl, bih_e,
            hebch, Whh_e_b, bhh_e,
            h_e + (size_t)r0 * H_, (long long)B_ * H_,
            out_he + (size_t)r0 * H_, (long long)B_ * H_,
            henewch);
        // weighted projection into P planes
        mgemm<2, true><<<dim3(8, 4, 16), 256, 0, stream>>>(
            henewch, (long long)2048 * H_,
            W_proj_b, (long long)D_ * H_, 512, 512,
            b_proj, D_,
            Pch, (long long)2048 * D_, D_, H_,
            wts + (size_t)r0 * E_, E_, 1);
        reduce8_k<<<(2048 * 128 + 255) / 256, 256, 0, stream>>>(
            Pch, comb + (size_t)r0 * D_, 2048 * 128, 2048 * 128);
    }

    // ---- head ----
    head_k<<<B_ / 8, 256, 0, stream>>>(comb, W_head, b_head, out_logits);
}

// Round 10
// 635.254 us; speedup vs baseline: 1.2562x; 1.0584x over previous
//
#include <hip/hip_runtime.h>
#include <cstddef>
#include <cstdint>

// Problem constants
#define B_  4096
#define I_  512
#define L_  128
#define D_  512
#define E_  8
#define H_  512
#define HR_ 256
#define A_  32

typedef __attribute__((ext_vector_type(8))) __bf16 bf16x8;
typedef __attribute__((ext_vector_type(4))) __bf16 bf16x4;
typedef __attribute__((ext_vector_type(4))) float floatx4;

__device__ __forceinline__ float sigmoidf_(float x) { return 1.0f / (1.0f + __expf(-x)); }

__device__ __forceinline__ void load_lds16(const void* g, void* l) {
    __builtin_amdgcn_global_load_lds((__attribute__((address_space(1))) void*)g,
                                     (__attribute__((address_space(3))) void*)l, 16, 0, 0);
}

struct HiLo { __bf16 h, l; };
__device__ __forceinline__ HiLo hi_lo(float v) {
    HiLo r;
    r.h = (__bf16)v;
    r.l = (__bf16)(v - (float)r.h);
    return r;
}
__device__ __forceinline__ void split4(float4 v, bf16x4& hi, bf16x4& lo) {
    HiLo a = hi_lo(v.x), b = hi_lo(v.y), c = hi_lo(v.z), d = hi_lo(v.w);
    hi = (bf16x4){a.h, b.h, c.h, d.h};
    lo = (bf16x4){a.l, b.l, c.l, d.l};
}

// =====================================================================
// LDS subtile swizzle (all MFMA kernels): each global_load_lds writes one
// 1024-B subtile = 16 rows x 4 segs (of 8 bf16 = 16 B). Slot s (= staging
// lane) holds (row = s>>2, seg = (s&3) ^ ((s>>3)&3)).
//  - STAGING: lane L fetches row L>>2, seg (L&3)^((L>>3)&3): the 4 lanes of
//    a row fetch the SAME 64-B chunk (permuted order) -> coalescing kept.
//  - READ: lane L needs (row r=L&15, seg q=L>>4) -> slot r*4 + (q^((r>>1)&3)).
//    Each 4-bank group hit exactly 2x = structural minimum (free on CDNA4).
//    [r8 measured: SQ_LDS_BANK_CONFLICT 10.5M -> 0, FETCH unchanged]
// =====================================================================
__device__ __forceinline__ int stage_seg(int lane) {
    return (lane & 3) ^ ((lane >> 3) & 3);
}
__device__ __forceinline__ int frag_off(int lane) {      // elements within subtile
    const int r = lane & 15, q = lane >> 4;
    return (r * 4 + (q ^ ((r >> 1) & 3))) * 8;
}

// ---------------- mega prep: all weight conversions + x|lang concat ---------
// One dispatch replaces 7 f2b/wcat2 launches + concat_cat (launch-gap removal).
// Items are float4 groups; if-chain dispatches by range (divergence only at
// range boundaries).
__global__ __launch_bounds__(256) void prep_all_k(
    const float* __restrict__ W_in,  const float* __restrict__ Wih_r,
    const float* __restrict__ Wih_e, const float* __restrict__ Whh_r,
    const float* __restrict__ Whh_e, const float* __restrict__ W_proj,
    const float* __restrict__ h_r,
    const float* __restrict__ x,     const float* __restrict__ lang,
    __bf16* __restrict__ W_in_hl,  __bf16* __restrict__ Wih_r_hl,
    __bf16* __restrict__ Wih_e_hl, __bf16* __restrict__ Whh_r_b,
    __bf16* __restrict__ Whh_e_b,  __bf16* __restrict__ W_proj_b,
    __bf16* __restrict__ hr_b,     __bf16* __restrict__ xcat)
{
    int i = blockIdx.x * 256 + threadIdx.x;

    // j1: Wih_e wcat2 (12288 x 512 fp32 -> 12288 x 1024 [hi|lo]), K4=128
    if (i < 1572864) {
        int row = i >> 7, c4 = i & 127;
        float4 v = ((const float4*)Wih_e)[i];
        bf16x4 hi, lo; split4(v, hi, lo);
        __bf16* dst = Wih_e_hl + (size_t)row * 1024 + c4 * 4;
        *(bf16x4*)(dst)       = hi;
        *(bf16x4*)(dst + 512) = lo;
        return;
    }
    i -= 1572864;
    // j2: Whh_e f2b (8*1536*512 fp32 -> bf16)
    if (i < 1572864) {
        float4 v = ((const float4*)Whh_e)[i];
        bf16x4 o = { (__bf16)v.x, (__bf16)v.y, (__bf16)v.z, (__bf16)v.w };
        *(bf16x4*)(Whh_e_b + (size_t)i * 4) = o;
        return;
    }
    i -= 1572864;
    // j3: concat [x|lang] -> xcat (B,1920) = [hi|hi|lo], 160 groups/row
    if (i < 655360) {
        int b = i / 160, c = i - b * 160;
        float4 v;
        if (c < 128) v = ((const float4*)x)[(size_t)b * 128 + c];
        else         v = ((const float4*)lang)[(size_t)b * 32 + (c - 128)];
        bf16x4 hi, lo; split4(v, hi, lo);
        __bf16* dst = xcat + (size_t)b * 1920 + c * 4;
        *(bf16x4*)(dst)        = hi;
        *(bf16x4*)(dst + 640)  = hi;
        *(bf16x4*)(dst + 1280) = lo;
        return;
    }
    i -= 655360;
    // j4: W_proj f2b (8*512*512)
    if (i < 524288) {
        float4 v = ((const float4*)W_proj)[i];
        bf16x4 o = { (__bf16)v.x, (__bf16)v.y, (__bf16)v.z, (__bf16)v.w };
        *(bf16x4*)(W_proj_b + (size_t)i * 4) = o;
        return;
    }
    i -= 524288;
    // j5: h_r f2b (B*256)
    if (i < 262144) {
        float4 v = ((const float4*)h_r)[i];
        bf16x4 o = { (__bf16)v.x, (__bf16)v.y, (__bf16)v.z, (__bf16)v.w };
        *(bf16x4*)(hr_b + (size_t)i * 4) = o;
        return;
    }
    i -= 262144;
    // j6: Wih_r wcat2 (768 x 512 -> 768 x 1024 [hi|lo]), K4=128
    if (i < 98304) {
        int row = i >> 7, c4 = i & 127;
        float4 v = ((const float4*)Wih_r)[i];
        bf16x4 hi, lo; split4(v, hi, lo);
        __bf16* dst = Wih_r_hl + (size_t)row * 1024 + c4 * 4;
        *(bf16x4*)(dst)       = hi;
        *(bf16x4*)(dst + 512) = lo;
        return;
    }
    i -= 98304;
    // j7: W_in wcat2 (512 x 640 -> 512 x 1280 [hi|lo]), K4=160
    if (i < 81920) {
        int row = i / 160, c4 = i - row * 160;
        float4 v = ((const float4*)W_in)[i];
        bf16x4 hi, lo; split4(v, hi, lo);
        __bf16* dst = W_in_hl + (size_t)row * 1280 + c4 * 4;
        *(bf16x4*)(dst)       = hi;
        *(bf16x4*)(dst + 640) = lo;
        return;
    }
    i -= 81920;
    // j8: Whh_r f2b (768*256)
    if (i < 49152) {
        float4 v = ((const float4*)Whh_r)[i];
        bf16x4 o = { (__bf16)v.x, (__bf16)v.y, (__bf16)v.z, (__bf16)v.w };
        *(bf16x4*)(Whh_r_b + (size_t)i * 4) = o;
    }
}

// h_e chunk convert: (E, B, H) fp32 rows [r0, r0+2048) -> (E, 2048, H) bf16
__global__ __launch_bounds__(256) void f2bhe_k(const float* __restrict__ he,
                                               __bf16* __restrict__ dst, int r0) {
    int i4 = blockIdx.x * 256 + threadIdx.x;    // over 8*2048*128
    int e   = i4 >> 18;
    int rem = i4 & 262143;
    int row = rem >> 7;
    int c4  = rem & 127;
    float4 v = ((const float4*)he)[(size_t)e * (B_ * 128) + (size_t)(r0 + row) * 128 + c4];
    bf16x4 o = { (__bf16)v.x, (__bf16)v.y, (__bf16)v.z, (__bf16)v.w };
    *(bf16x4*)(dst + (size_t)i4 * 4) = o;
}

// ---------------- MFMA GEMM 128x128 (2-phase dbuf, XOR-swizzled subtiles) ---
template<int MODE, bool XORD>
__global__ __launch_bounds__(256) void mgemm(
    const __bf16* __restrict__ A, long long aBatch,
    const __bf16* __restrict__ Bw, long long bBatch, int bRS, int kWrap,
    const float* __restrict__ bias, long long biasBatch,
    float* __restrict__ Cv, long long cBatch,
    int N, int K,
    const float* __restrict__ scale, int sstride, int szBatch)
{
    constexpr int ASZ = 128 * 32;
    __shared__ __align__(16) __bf16 As[2 * ASZ];
    __shared__ __align__(16) __bf16 Bs[2 * ASZ];

    const int tid  = threadIdx.x;
    const int w    = tid >> 6;
    const int lane = tid & 63;
    const int m0 = (XORD ? blockIdx.z : blockIdx.x) * 128;
    const int n0 = blockIdx.y * 128;
    const int z  = XORD ? blockIdx.x : blockIdx.z;

    const int lrow = lane >> 2;
    const int lsegx = stage_seg(lane);
    const __bf16* Ag0 = A + (size_t)z * aBatch + (size_t)(m0 + w * 32 + lrow) * K + lsegx * 8;
    const __bf16* Ag1 = Ag0 + (size_t)16 * K;
    const __bf16* Bg0 = Bw + (size_t)z * bBatch + (size_t)(n0 + w * 32 + lrow) * bRS + lsegx * 8;
    const __bf16* Bg1 = Bg0 + (size_t)16 * bRS;

    const int wm = w & 1, wn = w >> 1;
    const int lr16 = lane & 15;
    const int lq   = lane >> 4;
    const int fro  = frag_off(lane);

    floatx4 acc[4][4];
#pragma unroll
    for (int i = 0; i < 4; ++i)
#pragma unroll
        for (int j = 0; j < 4; ++j) acc[i][j] = (floatx4){0.f, 0.f, 0.f, 0.f};

    const int NSTEP = K >> 5;

    auto STAGE = [&](int s, int buf) {
        const int k0 = s << 5;
        const int kb = (k0 < kWrap) ? k0 : (k0 - kWrap);
        __bf16* al = As + buf * ASZ + (w * 32) * 32;
        __bf16* bl = Bs + buf * ASZ + (w * 32) * 32;
        load_lds16(Ag0 + k0, al);
        load_lds16(Ag1 + k0, al + 16 * 32);
        load_lds16(Bg0 + kb, bl);
        load_lds16(Bg1 + kb, bl + 16 * 32);
    };

    int cur = 0;
    STAGE(0, 0);
    __syncthreads();
    for (int s = 0; s < NSTEP; ++s) {
        if (s + 1 < NSTEP) STAGE(s + 1, cur ^ 1);

        const __bf16* Af = As + cur * ASZ + wm * 2048 + fro;
        const __bf16* Bf = Bs + cur * ASZ + wn * 2048 + fro;
        bf16x8 af[4], bfr[4];
#pragma unroll
        for (int t = 0; t < 4; ++t) {
            af[t]  = *(const bf16x8*)(Af + t * 512);
            bfr[t] = *(const bf16x8*)(Bf + t * 512);
        }
#pragma unroll
        for (int tm = 0; tm < 4; ++tm)
#pragma unroll
            for (int tn = 0; tn < 4; ++tn)
                acc[tm][tn] = __builtin_amdgcn_mfma_f32_16x16x32_bf16(af[tm], bfr[tn], acc[tm][tn], 0, 0, 0);

        __syncthreads();
        cur ^= 1;
    }

    const float* biasz = bias + (size_t)z * biasBatch;
    const int sz = z * szBatch;
#pragma unroll
    for (int tm = 0; tm < 4; ++tm) {
        const int mbase = m0 + wm * 64 + tm * 16 + lq * 4;
#pragma unroll
        for (int r = 0; r < 4; ++r) {
            const int m = mbase + r;
            float wsc = 0.f;
            if (MODE == 2) wsc = scale[(size_t)m * sstride + sz];
#pragma unroll
            for (int tn = 0; tn < 4; ++tn) {
                const int n = n0 + wn * 64 + tn * 16 + lr16;
                float v = acc[tm][tn][r] + biasz[n];
                const size_t ci = (size_t)z * cBatch + (size_t)m * N + n;
                if (MODE == 0) Cv[ci] = v;
                else           Cv[ci] = wsc * v;
            }
        }
    }
}

// ---------------- MFMA GEMM 64x128 (small-M tiles for grid-starved GEMMs) ---
// Used for the input projection (grid 64x4 = 256 blocks vs 128) and router gx
// (64x6 = 384 vs 192): 2-3x resident blocks on the 256-CU machine.
// MODE 0: C fp32 = acc+bias.
// MODE 3: write xp_cat [hi|hi|lo] bf16 directly (row stride 1536) -- fuses
//         the old split2cat kernel; identical arithmetic (same fp32 v split).
template<int MODE>
__global__ __launch_bounds__(256) void mgemm64(
    const __bf16* __restrict__ A,
    const __bf16* __restrict__ Bw, int bRS, int kWrap,
    const float* __restrict__ bias,
    void* __restrict__ Cv,
    int N, int K)
{
    constexpr int ASZ = 64 * 32;    // 2048 elems, 4 subtiles
    constexpr int BSZ = 128 * 32;   // 4096 elems, 8 subtiles
    __shared__ __align__(16) __bf16 As[2 * ASZ];
    __shared__ __align__(16) __bf16 Bs[2 * BSZ];

    const int tid  = threadIdx.x;
    const int w    = tid >> 6;      // wave 0..3 -> output cols w*32..+32
    const int lane = tid & 63;
    const int m0 = blockIdx.x * 64;
    const int n0 = blockIdx.y * 128;

    const int lrow = lane >> 2;
    const int lsegx = stage_seg(lane);
    // staging: wave w loads A subtile w (rows m0+w*16..+16) and B subtiles 2w,2w+1
    const __bf16* Ag  = A + (size_t)(m0 + w * 16 + lrow) * K + lsegx * 8;
    const __bf16* Bg0 = Bw + (size_t)(n0 + w * 32 + lrow) * bRS + lsegx * 8;
    const __bf16* Bg1 = Bg0 + (size_t)16 * bRS;

    const int lr16 = lane & 15;
    const int lq   = lane >> 4;
    const int fro  = frag_off(lane);

    floatx4 acc[4][2];
#pragma unroll
    for (int i = 0; i < 4; ++i)
#pragma unroll
        for (int j = 0; j < 2; ++j) acc[i][j] = (floatx4){0.f, 0.f, 0.f, 0.f};

    const int NSTEP = K >> 5;

    auto STAGE = [&](int s, int buf) {
        const int k0 = s << 5;
        const int kb = (k0 < kWrap) ? k0 : (k0 - kWrap);
        __bf16* al = As + buf * ASZ + w * 512;
        __bf16* bl = Bs + buf * BSZ + (w * 2) * 512;
        load_lds16(Ag + k0, al);
        load_lds16(Bg0 + kb, bl);
        load_lds16(Bg1 + kb, bl + 512);
    };

    int cur = 0;
    STAGE(0, 0);
    __syncthreads();
    for (int s = 0; s < NSTEP; ++s) {
        if (s + 1 < NSTEP) STAGE(s + 1, cur ^ 1);

        const __bf16* Af = As + cur * ASZ + fro;
        const __bf16* Bf = Bs + cur * BSZ + (w * 2) * 512 + fro;
        bf16x8 af[4], bfr[2];
#pragma unroll
        for (int t = 0; t < 4; ++t) af[t] = *(const bf16x8*)(Af + t * 512);
#pragma unroll
        for (int t = 0; t < 2; ++t) bfr[t] = *(const bf16x8*)(Bf + t * 512);
#pragma unroll
        for (int tm = 0; tm < 4; ++tm)
#pragma unroll
            for (int tn = 0; tn < 2; ++tn)
                acc[tm][tn] = __builtin_amdgcn_mfma_f32_16x16x32_bf16(af[tm], bfr[tn], acc[tm][tn], 0, 0, 0);

        __syncthreads();
        cur ^= 1;
    }

#pragma unroll
    for (int tm = 0; tm < 4; ++tm) {
#pragma unroll
        for (int r = 0; r < 4; ++r) {
            const int m = m0 + tm * 16 + lq * 4 + r;
#pragma unroll
            for (int tn = 0; tn < 2; ++tn) {
                const int n = n0 + w * 32 + tn * 16 + lr16;
                float v = acc[tm][tn][r] + bias[n];
                if (MODE == 0) {
                    ((float*)Cv)[(size_t)m * N + n] = v;
                } else {           // MODE 3: xp_cat [hi|hi|lo], row stride 1536
                    HiLo hl = hi_lo(v);
                    __bf16* xc = (__bf16*)Cv + (size_t)m * 1536 + n;
                    xc[0]    = hl.h;
                    xc[512]  = hl.h;
                    xc[1024] = hl.l;
                }
            }
        }
    }
}

// ---------------- router fused gh-GEMM + GRU (XOR-swizzled subtiles) ---------
template<int HD, bool WRITE_HNEW, bool XORD>
__global__ __launch_bounds__(256) void fgru(
    const __bf16* __restrict__ Ab, long long aBatch,     // (z, Mtot, HD) bf16
    const __bf16* __restrict__ Whh, long long wBatch,    // (z, 3HD, HD) bf16
    const float* __restrict__ bhh, long long bhhBatch,   // (z, 3HD)
    const float* __restrict__ gx, long long gxBatch,     // (z, Mtot, 3HD) fp32
    const float* __restrict__ hprev, long long hBatch,   // (z, ..., HD) fp32
    float* __restrict__ hout, long long hoBatch,         // fp32
    __bf16* __restrict__ hnew, long long hnBatch)        // bf16
{
    __shared__ __align__(16) __bf16 As[128 * 32];
    __shared__ __align__(16) __bf16 Bs[192 * 32];

    const int tid  = threadIdx.x;
    const int w    = tid >> 6;
    const int lane = tid & 63;
    const int m0 = (XORD ? blockIdx.z : blockIdx.x) * 128;
    const int j0 = blockIdx.y * 64;
    const int z  = XORD ? blockIdx.x : blockIdx.z;

    const int lrow = lane >> 2;
    const int lsegx = stage_seg(lane);
    const __bf16* Ag0 = Ab + (size_t)z * aBatch + (size_t)(m0 + w * 32 + lrow) * HD + lsegx * 8;
    const __bf16* Ag1 = Ag0 + (size_t)16 * HD;
    __bf16* Al0 = As + (w * 32) * 32;
    __bf16* Al1 = Al0 + 16 * 32;

    const __bf16* Wz = Whh + (size_t)z * wBatch;
    const __bf16* Bg[3];
    __bf16* Bl[3];
#pragma unroll
    for (int i = 0; i < 3; ++i) {
        const int r = (w * 3 + i) * 16 + lrow;          // 0..191
        const int gate = r >> 6;
        const int grow = gate * HD + j0 + (r & 63);
        Bg[i] = Wz + (size_t)grow * HD + lsegx * 8;
        Bl[i] = Bs + ((w * 3 + i) * 16) * 32;
    }

    const int mh = w & 1, nh = w >> 1;
    const int lr16 = lane & 15;
    const int lq   = lane >> 4;
    const int fro  = frag_off(lane);
    const __bf16* Af = As + mh * 2048 + fro;
    const __bf16* Bf = Bs + nh * 1024 + fro;

    floatx4 acc[3][4][2];
#pragma unroll
    for (int g = 0; g < 3; ++g)
#pragma unroll
        for (int i = 0; i < 4; ++i)
#pragma unroll
            for (int j = 0; j < 2; ++j) acc[g][i][j] = (floatx4){0.f, 0.f, 0.f, 0.f};

    for (int k0 = 0; k0 < HD; k0 += 32) {
        __syncthreads();
        load_lds16(Ag0 + k0, Al0);
        load_lds16(Ag1 + k0, Al1);
#pragma unroll
        for (int i = 0; i < 3; ++i) load_lds16(Bg[i] + k0, Bl[i]);
        __syncthreads();

        bf16x8 af[4], bf[3][2];
#pragma unroll
        for (int t = 0; t < 4; ++t) af[t] = *(const bf16x8*)(Af + t * 512);
#pragma unroll
        for (int g = 0; g < 3; ++g)
#pragma unroll
            for (int tn = 0; tn < 2; ++tn)
                bf[g][tn] = *(const bf16x8*)(Bf + (g * 4 + tn) * 512);
#pragma unroll
        for (int g = 0; g < 3; ++g)
#pragma unroll
            for (int tm = 0; tm < 4; ++tm)
#pragma unroll
                for (int tn = 0; tn < 2; ++tn)
                    acc[g][tm][tn] = __builtin_amdgcn_mfma_f32_16x16x32_bf16(af[tm], bf[g][tn], acc[g][tm][tn], 0, 0, 0);
    }

    const float* bhhz = bhh + (size_t)z * bhhBatch;
#pragma unroll
    for (int tm = 0; tm < 4; ++tm) {
#pragma unroll
        for (int rr = 0; rr < 4; ++rr) {
            const int row = m0 + mh * 64 + tm * 16 + lq * 4 + rr;
            const float* gxrow = gx + (size_t)z * gxBatch + (size_t)row * (3 * HD);
            const float* hrow  = hprev + (size_t)z * hBatch + (size_t)row * HD;
#pragma unroll
            for (int tn = 0; tn < 2; ++tn) {
                const int j = j0 + nh * 32 + tn * 16 + lr16;
                float ghr = acc[0][tm][tn][rr] + bhhz[j];
                float ghz = acc[1][tm][tn][rr] + bhhz[HD + j];
                float ghn = acc[2][tm][tn][rr] + bhhz[2 * HD + j];
                float r  = sigmoidf_(gxrow[j] + ghr);
                float zz = sigmoidf_(gxrow[HD + j] + ghz);
                float n  = tanhf(gxrow[2 * HD + j] + r * ghn);
                float hv = hrow[j];
                float o  = (1.f - zz) * n + zz * hv;
                hout[(size_t)z * hoBatch + (size_t)row * HD + j] = o;
                if (WRITE_HNEW)
                    hnew[(size_t)z * hnBatch + (size_t)row * HD + j] = (__bf16)o;
            }
        }
    }
}

// ---------------- fused expert gx+gh GEMM + GRU (depth-3 + XOR swizzle) ------
template<int MROWS>
__global__ __launch_bounds__(256, 2) void fxgru_k(
    const __bf16* __restrict__ xpc,     // (MROWS, 1536) chunk [hi|hi|lo]
    const __bf16* __restrict__ Wih,     // (E, 1536, 1024) rows [hi|lo]
    const float* __restrict__ bih,      // (E, 1536)
    const __bf16* __restrict__ heb,     // (E, MROWS, 512) bf16 h_prev chunk
    const __bf16* __restrict__ Whh,     // (E, 1536, 512) bf16
    const float* __restrict__ bhh,      // (E, 1536)
    const float* __restrict__ hprev,    // (E, B, 512) fp32, chunk base
    long long hBatch,
    float* __restrict__ hout,           // (E, B, 512) fp32, chunk base
    long long hoBatch,
    __bf16* __restrict__ hnew)          // (E, MROWS, 512) bf16
{
    constexpr int ASZ = 128 * 32;
    constexpr int BSZ = 192 * 32;
    __shared__ __align__(16) __bf16 As[3 * ASZ];   // 24 KB
    __shared__ __align__(16) __bf16 Bs[3 * BSZ];   // 36 KB  (total 60 KB, 2 blk/CU)

    const int tid  = threadIdx.x;
    const int w    = tid >> 6;
    const int lane = tid & 63;
    const int z  = blockIdx.x;          // expert -> XCD
    const int j0 = blockIdx.y * 64;
    const int m0 = blockIdx.z * 128;

    const int lrow = lane >> 2;         // staging row (coalesced 64-B chunks)
    const int lsegx = stage_seg(lane);  // XOR'd segment
    const int aoff = (w * 32) * 32;
    int BlOff[3];
#pragma unroll
    for (int i = 0; i < 3; ++i) BlOff[i] = ((w * 3 + i) * 16) * 32;

    const int mh = w & 1, nh = w >> 1;
    const int lr16 = lane & 15;
    const int lq   = lane >> 4;
    const int fro  = frag_off(lane);

    floatx4 acc[3][4][2];   // gate r/z: gx+gh summed in place; gate n: gx only
    floatx4 accn[4][2];     // gh n-gate (kept separate for r*gh_n)
#pragma unroll
    for (int g = 0; g < 3; ++g)
#pragma unroll
        for (int i = 0; i < 4; ++i)
#pragma unroll
            for (int j = 0; j < 2; ++j) acc[g][i][j] = (floatx4){0.f, 0.f, 0.f, 0.f};
#pragma unroll
    for (int i = 0; i < 4; ++i)
#pragma unroll
        for (int j = 0; j < 2; ++j) accn[i][j] = (floatx4){0.f, 0.f, 0.f, 0.f};

    auto COMPA = [&](int buf) {
        const __bf16* Af = As + buf * ASZ + mh * 2048 + fro;
        const __bf16* Bf = Bs + buf * BSZ + nh * 1024 + fro;
        bf16x8 af[4], bf[3][2];
#pragma unroll
        for (int t = 0; t < 4; ++t) af[t] = *(const bf16x8*)(Af + t * 512);
#pragma unroll
        for (int g = 0; g < 3; ++g)
#pragma unroll
            for (int tn = 0; tn < 2; ++tn)
                bf[g][tn] = *(const bf16x8*)(Bf + (g * 4 + tn) * 512);
#pragma unroll
        for (int g = 0; g < 3; ++g)
#pragma unroll
            for (int tm = 0; tm < 4; ++tm)
#pragma unroll
                for (int tn = 0; tn < 2; ++tn)
                    acc[g][tm][tn] = __builtin_amdgcn_mfma_f32_16x16x32_bf16(af[tm], bf[g][tn], acc[g][tm][tn], 0, 0, 0);
    };
    auto COMPB = [&](int buf) {
        const __bf16* Af = As + buf * ASZ + mh * 2048 + fro;
        const __bf16* Bf = Bs + buf * BSZ + nh * 1024 + fro;
        bf16x8 af[4], bf[3][2];
#pragma unroll
        for (int t = 0; t < 4; ++t) af[t] = *(const bf16x8*)(Af + t * 512);
#pragma unroll
        for (int g = 0; g < 3; ++g)
#pragma unroll
            for (int tn = 0; tn < 2; ++tn)
                bf[g][tn] = *(const bf16x8*)(Bf + (g * 4 + tn) * 512);
#pragma unroll
        for (int tm = 0; tm < 4; ++tm)
#pragma unroll
            for (int tn = 0; tn < 2; ++tn) {
                acc[0][tm][tn] = __builtin_amdgcn_mfma_f32_16x16x32_bf16(af[tm], bf[0][tn], acc[0][tm][tn], 0, 0, 0);
                acc[1][tm][tn] = __builtin_amdgcn_mfma_f32_16x16x32_bf16(af[tm], bf[1][tn], acc[1][tm][tn], 0, 0, 0);
                accn[tm][tn]   = __builtin_amdgcn_mfma_f32_16x16x32_bf16(af[tm], bf[2][tn], accn[tm][tn], 0, 0, 0);
            }
    };

    // wait for own tile-loads (leave N in flight) then workgroup barrier
#define TILE_WAIT(N) do { \
        asm volatile("s_waitcnt vmcnt(" #N ")" ::: "memory"); \
        __builtin_amdgcn_s_barrier(); \
        __builtin_amdgcn_sched_barrier(0); \
    } while (0)
#define READ_DONE() do { \
        __builtin_amdgcn_sched_barrier(0); \
        __builtin_amdgcn_s_barrier(); \
    } while (0)

    int cur = 0;
    // ================= phase A: gx, tiles 0..47 =================
    {
        const __bf16* AgA0 = xpc + (size_t)(m0 + w * 32 + lrow) * 1536 + lsegx * 8;
        const __bf16* AgA1 = AgA0 + (size_t)16 * 1536;
        const __bf16* WihZ = Wih + (size_t)z * (1536 * 1024);
        const __bf16* BgA[3];
#pragma unroll
        for (int i = 0; i < 3; ++i) {
            const int r = (w * 3 + i) * 16 + lrow;          // 0..191
            const int grow = (r >> 6) * 512 + j0 + (r & 63);
            BgA[i] = WihZ + (size_t)grow * 1024 + lsegx * 8;
        }
        auto STAGE_A = [&](int s, int buf) {
            const int k0 = s << 5;
            const int kb = (k0 < 1024) ? k0 : (k0 - 1024);
            __bf16* al = As + buf * ASZ + aoff;
            __bf16* bl = Bs + buf * BSZ;
            load_lds16(AgA0 + k0, al);
            load_lds16(AgA1 + k0, al + 16 * 32);
#pragma unroll
            for (int i = 0; i < 3; ++i) load_lds16(BgA[i] + kb, bl + BlOff[i]);
        };

        STAGE_A(0, 0);
        STAGE_A(1, 1);
        STAGE_A(2, 2);                    // 15 loads in flight
        for (int s = 0; s < 45; ++s) {    // tiles 0..44; stage tiles 3..47
            TILE_WAIT(10);
            COMPA(cur);
            READ_DONE();
            STAGE_A(s + 3, cur);
            cur = (cur == 2) ? 0 : cur + 1;
        }
    }
    // ================= boundary: finish A tiles 45..47, stage B 0..2 =========
    {
        const __bf16* AgB0 = heb + (size_t)z * (MROWS * 512)
                                 + (size_t)(m0 + w * 32 + lrow) * 512 + lsegx * 8;
        const __bf16* AgB1 = AgB0 + (size_t)16 * 512;
        const __bf16* WhhZ = Whh + (size_t)z * (1536 * 512);
        const __bf16* BgB[3];
#pragma unroll
        for (int i = 0; i < 3; ++i) {
            const int r = (w * 3 + i) * 16 + lrow;
            const int grow = (r >> 6) * 512 + j0 + (r & 63);
            BgB[i] = WhhZ + (size_t)grow * 512 + lsegx * 8;
        }
        auto STAGE_B = [&](int t, int buf) {
            const int k0 = t << 5;
            __bf16* al = As + buf * ASZ + aoff;
            __bf16* bl = Bs + buf * BSZ;
            load_lds16(AgB0 + k0, al);
            load_lds16(AgB1 + k0, al + 16 * 32);
#pragma unroll
            for (int i = 0; i < 3; ++i) load_lds16(BgB[i] + k0, bl + BlOff[i]);
        };

#pragma unroll
        for (int q = 0; q < 3; ++q) {     // A tiles 45,46,47; stage B 0,1,2
            TILE_WAIT(10);
            COMPA(cur);
            READ_DONE();
            STAGE_B(q, cur);
            cur = (cur == 2) ? 0 : cur + 1;
        }
        // ================= phase B: gh, tiles 0..15 =================
        for (int t = 0; t < 13; ++t) {    // stage tiles 3..15
            TILE_WAIT(10);
            COMPB(cur);
            READ_DONE();
            STAGE_B(t + 3, cur);
            cur = (cur == 2) ? 0 : cur + 1;
        }
        TILE_WAIT(10);                    // tile 13 (14,15 in flight)
        COMPB(cur);
        cur = (cur == 2) ? 0 : cur + 1;
        TILE_WAIT(5);                     // tile 14
        COMPB(cur);
        cur = (cur == 2) ? 0 : cur + 1;
        TILE_WAIT(0);                     // tile 15
        COMPB(cur);
    }
#undef TILE_WAIT
#undef READ_DONE

    // ---- GRU epilogue ----
    const float* bihz = bih + (size_t)z * 1536;
    const float* bhhz = bhh + (size_t)z * 1536;
#pragma unroll
    for (int tm = 0; tm < 4; ++tm) {
#pragma unroll
        for (int rr = 0; rr < 4; ++rr) {
            const int row = m0 + mh * 64 + tm * 16 + lq * 4 + rr;
            const float* hrow = hprev + (size_t)z * hBatch + (size_t)row * 512;
#pragma unroll
            for (int tn = 0; tn < 2; ++tn) {
                const int j = j0 + nh * 32 + tn * 16 + lr16;
                float gr  = acc[0][tm][tn][rr] + bihz[j] + bhhz[j];
                float gz  = acc[1][tm][tn][rr] + bihz[512 + j] + bhhz[512 + j];
                float gxn = acc[2][tm][tn][rr] + bihz[1024 + j];
                float ghn = accn[tm][tn][rr] + bhhz[1024 + j];
                float r  = sigmoidf_(gr);
                float zz = sigmoidf_(gz);
                float n  = tanhf(gxn + r * ghn);
                float hv = hrow[j];
                float o  = (1.f - zz) * n + zz * hv;
                hout[(size_t)z * hoBatch + (size_t)row * 512 + j] = o;
                hnew[(size_t)z * (MROWS * 512) + (size_t)row * 512 + j] = (__bf16)o;
            }
        }
    }
}

// ---------------- router fc + softmax ----------------
__global__ __launch_bounds__(256) void fc_softmax_k(const float* __restrict__ hr,
                                                    const float* __restrict__ Wfc,
                                                    const float* __restrict__ bfc,
                                                    float* __restrict__ wts) {
    int lane = threadIdx.x & 63;
    int wave = threadIdx.x >> 6;
    int rg = lane >> 3;
    int e  = lane & 7;
    int b  = blockIdx.x * 32 + wave * 8 + rg;
    const float* h = hr + (size_t)b * HR_;
    const float* w = Wfc + (size_t)e * HR_;
    float acc = 0.0f;
#pragma unroll 4
    for (int k = 0; k < HR_; k += 4) {
        float4 hv = *(const float4*)(h + k);
        float4 wv = *(const float4*)(w + k);
        acc += hv.x * wv.x + hv.y * wv.y + hv.z * wv.z + hv.w * wv.w;
    }
    acc += bfc[e];
    float m = acc;
    for (int off = 4; off; off >>= 1) m = fmaxf(m, __shfl_xor(m, off, 8));
    float ex = __expf(acc - m);
    float s = ex;
    for (int off = 4; off; off >>= 1) s += __shfl_xor(s, off, 8);
    wts[(size_t)b * E_ + e] = ex / s;
}

// ---------------- reduce 8 expert P planes (chunk) -> comb ----------------
__global__ __launch_bounds__(256) void reduce8_k(const float* __restrict__ P,
                                                 float* __restrict__ comb,
                                                 int n4, int ps4) {
    int i = blockIdx.x * 256 + threadIdx.x;
    if (i >= n4) return;
    float4 s = ((const float4*)P)[i];
#pragma unroll
    for (int e = 1; e < E_; ++e) {
        float4 v = ((const float4*)P)[i + (size_t)e * ps4];
        s.x += v.x; s.y += v.y; s.z += v.z; s.w += v.w;
    }
    ((float4*)comb)[i] = s;
}

// ---------------- head ----------------
__global__ __launch_bounds__(256) void head_k(const float* __restrict__ comb,
                                              const float* __restrict__ Wh,
                                              const float* __restrict__ bh,
                                              float* __restrict__ out) {
    __shared__ float hs[8][512];
    int b0 = blockIdx.x * 8;
    for (int i = threadIdx.x; i < 8 * 128; i += 256) {
        int rr = i >> 7, cc = i & 127;
        ((float4*)hs[rr])[cc] = ((const float4*)(comb + (size_t)(b0 + rr) * 512))[cc];
    }
    __syncthreads();
    int r = threadIdx.x >> 5, c = threadIdx.x & 31;
    const float* wrow = Wh + (size_t)c * 512;
    float acc = 0.f;
    for (int k = 0; k < 512; k += 4) {
        float4 wv = *(const float4*)(wrow + k);
        float4 hv = *(const float4*)(&hs[r][k]);
        acc += hv.x * wv.x + hv.y * wv.y + hv.z * wv.z + hv.w * wv.w;
    }
    out[(size_t)(b0 + r) * 32 + c] = acc + bh[c];
}

// ---------------- launcher ----------------
extern "C" void kernel_launch(void* const* d_in, const int* in_sizes, int n_in,
                              void* d_out, int out_size, void* d_ws, size_t ws_size,
                              hipStream_t stream)
{
    const float* x      = (const float*)d_in[0];
    const float* lang   = (const float*)d_in[1];
    const float* h_r    = (const float*)d_in[2];
    const float* h_e    = (const float*)d_in[3];
    const float* W_in   = (const float*)d_in[4];
    const float* b_in   = (const float*)d_in[5];
    const float* Wih_r  = (const float*)d_in[6];
    const float* Whh_r  = (const float*)d_in[7];
    const float* bih_r  = (const float*)d_in[8];
    const float* bhh_r  = (const float*)d_in[9];
    const float* W_fc   = (const float*)d_in[10];
    const float* b_fc   = (const float*)d_in[11];
    const float* Wih_e  = (const float*)d_in[12];
    const float* Whh_e  = (const float*)d_in[13];
    const float* bih_e  = (const float*)d_in[14];
    const float* bhh_e  = (const float*)d_in[15];
    const float* W_proj = (const float*)d_in[16];
    const float* b_proj = (const float*)d_in[17];
    const float* W_head = (const float*)d_in[18];
    const float* b_head = (const float*)d_in[19];

    float* out_logits = (float*)d_out;                 // B*A
    float* out_hr     = out_logits + (size_t)B_ * A_;  // B*HR
    float* out_he     = out_hr + (size_t)B_ * HR_;     // E*B*H

    char* wsb = (char*)d_ws;
    size_t off = 0;
    auto alloc = [&](size_t bytes) -> char* {
        char* p = wsb + off;
        off = (off + bytes + 255) & ~(size_t)255;
        return p;
    };

    // ---- persistent (through expert loop): 63.0 MB ----
    __bf16* Wih_e_hl = (__bf16*)alloc((size_t)12288 * 1024 * 2);   // [hi|lo]
    __bf16* Whh_e_b  = (__bf16*)alloc((size_t)8 * 1536 * 512 * 2);
    __bf16* W_proj_b = (__bf16*)alloc((size_t)8 * 512 * 512 * 2);
    __bf16* xp_cat   = (__bf16*)alloc((size_t)B_ * 1536 * 2);      // [hi|hi|lo]
    float*  wts      = (float*)alloc((size_t)B_ * E_ * 4);
    float*  comb     = (float*)alloc((size_t)B_ * D_ * 4);

    // ---- region R: max(prep ~42 MB, chunk 67.1 MB) ----
    char* R = wsb + off;
    // prep-phase layout within R:
    __bf16* W_in_hl  = (__bf16*)(R);                                   // 512*1280*2  = 1.31 MB
    __bf16* Wih_r_hl = (__bf16*)(R + 1310720);                         // 768*1024*2  = 1.57 MB
    __bf16* Whh_r_b  = (__bf16*)(R + 1310720 + 1572864);               // 768*256*2   = 0.39 MB
    __bf16* hr_b     = (__bf16*)(R + 1310720 + 1572864 + 393216);      // B*256*2     = 2.10 MB
    char*   Rp       = R + 1310720 + 1572864 + 393216 + 2097152;
    __bf16* xcat_cat = (__bf16*)(Rp);                                  // B*1920*2    = 15.73 MB
    float*  gxr      = (float*)(Rp + 15728640 + 8388608);              // B*768*4     = 12.58 MB
    // chunk-phase layout within R (prep all dead by then), 2048-row super-chunks:
    float*  Pch      = (float*)(R);                                    // 8*2048*512*4 = 33.55 MB
    __bf16* hebch    = (__bf16*)(R + 33554432);                        // 8*2048*512*2 = 16.78 MB
    __bf16* henewch  = (__bf16*)(R + 33554432 + 16777216);             // 16.78 MB

    // ---- prep: all conversions + concat in ONE dispatch (was 8) ----
    prep_all_k<<<18816, 256, 0, stream>>>(
        W_in, Wih_r, Wih_e, Whh_r, Whh_e, W_proj, h_r, x, lang,
        W_in_hl, Wih_r_hl, Wih_e_hl, Whh_r_b, Whh_e_b, W_proj_b, hr_b, xcat_cat);

    // ---- input projection: 64-row tiles (256 blocks), writes xp_cat directly
    mgemm64<3><<<dim3(64, 4), 256, 0, stream>>>(
        xcat_cat, W_in_hl, 1280, 1280, b_in, xp_cat, 512, 1920);

    // ---- router: gx GEMM (64-row tiles, 384 blocks), fused gh+GRU, softmax
    mgemm64<0><<<dim3(64, 6), 256, 0, stream>>>(
        xp_cat, Wih_r_hl, 1024, 1024, bih_r, gxr, 768, 1536);
    fgru<HR_, false, false><<<dim3(32, 4, 1), 256, 0, stream>>>(
        hr_b, 0, Whh_r_b, 0, bhh_r, 0, gxr, 0, h_r, 0, out_hr, 0, nullptr, 0);
    fc_softmax_k<<<B_ / 32, 256, 0, stream>>>(out_hr, W_fc, b_fc, wts);

    // ---- experts: 2 super-chunks of 2048 rows; gx+gh+GRU fused per chunk ----
    // Grids are (expert, ..): gridDim.x == 8 == #XCDs -> one expert per XCD.
    for (int c = 0; c < 2; ++c) {
        const int r0 = c * 2048;
        f2bhe_k<<<(8 * 2048 * 128) / 256, 256, 0, stream>>>(h_e, hebch, r0);
        // fused gx-GEMM + gh-GEMM + GRU -> out_he (fp32) + henew (bf16)
        fxgru_k<2048><<<dim3(8, 8, 16), 256, 0, stream>>>(
            xp_cat + (size_t)r0 * 1536,
            Wih_e_hl, bih_e,
            hebch, Whh_e_b, bhh_e,
            h_e + (size_t)r0 * H_, (long long)B_ * H_,
            out_he + (size_t)r0 * H_, (long long)B_ * H_,
            henewch);
        // weighted projection into P planes
        mgemm<2, true><<<dim3(8, 4, 16), 256, 0, stream>>>(
            henewch, (long long)2048 * H_,
            W_proj_b, (long long)D_ * H_, 512, 512,
            b_proj, D_,
            Pch, (long long)2048 * D_, D_, H_,
            wts + (size_t)r0 * E_, E_, 1);
        reduce8_k<<<(2048 * 128 + 255) / 256, 256, 0, stream>>>(
            Pch, comb + (size_t)r0 * D_, 2048 * 128, 2048 * 128);
    }

    // ---- head ----
    head_k<<<B_ / 8, 256, 0, stream>>>(comb, W_head, b_head, out_logits);
}